// Round 13
// baseline (835.896 us; speedup 1.0000x reference)
//
#include <hip/hip_runtime.h>
#include <hip/hip_bf16.h>
#include <math.h>

#define DEV __device__ __forceinline__

constexpr int Bb   = 32;
constexpr int Nn   = 128;
constexpr int Ff   = 10;
constexpr int Dd   = 64;
constexpr int TOPK = 20;
constexpr int EXTRA= 25;
constexpr int BN   = 4096;   // B*N
constexpr int TBN  = 8192;   // 2*BN
constexpr int RC   = 16;     // r-chunks for split-K ef
constexpr int CAND_CAP = 1024;
constexpr int SUBCAP = 256;  // max needed 16-col subtiles per row in k_sel
constexpr int PV2CAP = 256;  // stage-2 pivot-bin candidate cap
constexpr float EPS   = 1e-5f;
constexpr float SLOPE = 0.2f;

// order-preserving float<->uint encoding (monotone: a<b  <=> fenc(a)<fenc(b))
DEV unsigned int fenc(float f){
  unsigned int b = __float_as_uint(f);
  return (b & 0x80000000u) ? ~b : (b | 0x80000000u);
}
DEV float fdec(unsigned int u){
  unsigned int b = (u & 0x80000000u) ? (u & 0x7FFFFFFFu) : ~u;
  return __uint_as_float(b);
}

// ---------------- generic zero ----------------
__global__ void k_zero(float* __restrict__ p, int n){
  int i = blockIdx.x*256 + threadIdx.x;
  if(i < n) p[i] = 0.f;
}

// ---------------- emb row norms ----------------
__global__ void k_emb_norm(const float* __restrict__ emb, float* __restrict__ norms){
  int i = blockIdx.x, d = threadIdx.x;
  float v = emb[i*Dd + d];
  float s = v*v;
  for(int o=32;o>0;o>>=1) s += __shfl_down(s, o, 64);
  if(d==0) norms[i] = fmaxf(sqrtf(s), 1e-12f);
}

// ---------------- emb cosine + top-20 per row: single-pass rank select ----------------
__global__ void k_emb_topk(const float* __restrict__ emb, const float* __restrict__ norms,
                           float* __restrict__ topv, int* __restrict__ topi){
  __shared__ float se[Dd];
  __shared__ float sc[Nn];
  int i = blockIdx.x, t = threadIdx.x;
  if(t < Dd) se[t] = emb[i*Dd + t];
  __syncthreads();
  float dot = 0.f;
  for(int d=0; d<Dd; d++) dot += se[d]*emb[t*Dd + d];
  float v = dot/(norms[i]*norms[t]);
  sc[t] = v;
  __syncthreads();
  int rank = 0;
  for(int j=0; j<Nn; j++){
    float vj = sc[j];
    rank += (vj > v) || (vj == v && j < t);
  }
  if(rank < TOPK){
    topv[i*TOPK + rank] = v;
    topi[i*TOPK + rank] = t;
  }
}

// ---------------- h = x@W1, si/sj attention logits ----------------
__global__ void k_h1(const float* __restrict__ data, const float* __restrict__ emb,
                     const float* __restrict__ W1, const float* __restrict__ ai1,
                     const float* __restrict__ aj1,
                     float* __restrict__ h, float* __restrict__ si, float* __restrict__ sj){
  int r = blockIdx.x, d = threadIdx.x;
  int node = r & (Nn-1);
  __shared__ float xr[Ff];
  if(d < Ff) xr[d] = data[r*Ff + d];
  __syncthreads();
  float hv = 0.f;
  #pragma unroll
  for(int f=0; f<Ff; f++) hv += xr[f]*W1[f*Dd + d];
  h[r*Dd + d] = hv;
  float e = emb[node*Dd + d];
  float a = hv*ai1[d] + e*ai1[Dd + d];
  float b = hv*aj1[d] + e*aj1[Dd + d];
  for(int o=32;o>0;o>>=1){ a += __shfl_down(a,o,64); b += __shfl_down(b,o,64); }
  if(d==0){ si[r] = a; sj[r] = b; }
}

// ---------------- layer-1 segment softmax + aggregation ----------------
__global__ void k_agg1(const float* __restrict__ h, const float* __restrict__ si,
                       const float* __restrict__ sj, const float* __restrict__ topv,
                       const int* __restrict__ topi, const float* __restrict__ bias1,
                       float* __restrict__ agg){
  int r = blockIdx.x, d = threadIdx.x;
  int b = r >> 7, node = r & (Nn-1);
  __shared__ float sal[TOPK];
  __shared__ int   ssrc[TOPK];
  if(d < TOPK){
    int s = b*Nn + topi[node*TOPK + d];
    float sc = si[r] + sj[s];
    sc = sc >= 0.f ? sc : SLOPE*sc;
    sal[d] = sc * topv[node*TOPK + d];
    ssrc[d] = s;
  }
  __syncthreads();
  float m = -INFINITY;
  #pragma unroll
  for(int k=0;k<TOPK;k++) m = fmaxf(m, sal[k]);
  float al[TOPK]; float ssum = 0.f;
  #pragma unroll
  for(int k=0;k<TOPK;k++){ al[k] = expf(sal[k]-m); ssum += al[k]; }
  float inv = 1.0f/fmaxf(ssum, 1e-12f);
  float acc = 0.f;
  #pragma unroll
  for(int k=0;k<TOPK;k++) acc += al[k]*inv*h[ssrc[k]*Dd + d];
  agg[r*Dd + d] = acc + bias1[d];
}

// ---------------- per-channel stats over BN rows (agg1) ----------------
__global__ void k_colstats(const float* __restrict__ x, float* __restrict__ mu, float* __restrict__ var){
  int c = blockIdx.x, t = threadIdx.x;
  float s = 0.f, s2 = 0.f;
  for(int r=t; r<BN; r+=256){ float v = x[r*Dd + c]; s += v; s2 += v*v; }
  __shared__ float ls[256], ls2[256];
  ls[t]=s; ls2[t]=s2; __syncthreads();
  for(int o=128;o>0;o>>=1){
    if(t<o){ ls[t]+=ls[t+o]; ls2[t]+=ls2[t+o]; }
    __syncthreads();
  }
  if(t==0){ float m = ls[0]/BN; mu[c]=m; var[c]=ls2[0]/BN - m*m; }
}

// ---------------- BN1 + relu -> g[0:BN] ----------------
__global__ void k_bnrelu1(const float* __restrict__ agg, const float* __restrict__ mu,
                          const float* __restrict__ var, const float* __restrict__ gamma,
                          const float* __restrict__ beta, float* __restrict__ g){
  int idx = blockIdx.x*256 + threadIdx.x;
  int c = idx & (Dd-1);
  float v = agg[idx];
  float y = gamma[c]*(v - mu[c])/sqrtf(var[c]+EPS) + beta[c];
  g[idx] = fmaxf(y, 0.f);
}

// ---------------- ef stage 1: partial P^T @ gcn tiles, non-atomic ----------------
__global__ __launch_bounds__(256) void k_ef1(const float* __restrict__ P, const float* __restrict__ gcn,
                                             float* __restrict__ part){
  __shared__ float Pt[16*128];
  __shared__ float Gt[16*64];
  int t = threadIdx.x;
  int jbase = blockIdx.x*128;
  int r0 = blockIdx.y*256;
  int row = t >> 4, col4 = (t & 15)*4;
  int tr = t >> 4, tc = t & 15;
  float acc[8][4] = {};
  for(int step=0; step<16; step++){
    int r = r0 + step*16;
    float4 pv0 = *(const float4*)&P[(size_t)(r+row)*BN + jbase + col4];
    float4 pv1 = *(const float4*)&P[(size_t)(r+row)*BN + jbase + col4 + 64];
    float4 gv  = *(const float4*)&gcn[(r+row)*Dd + col4];
    __syncthreads();
    *(float4*)&Pt[row*128 + col4]      = pv0;
    *(float4*)&Pt[row*128 + col4 + 64] = pv1;
    *(float4*)&Gt[row*64 + col4] = gv;
    __syncthreads();
    #pragma unroll
    for(int rr=0; rr<16; rr++){
      float4 pa0 = *(float4*)&Pt[rr*128 + tr*8];
      float4 pa1 = *(float4*)&Pt[rr*128 + tr*8 + 4];
      float4 gb  = *(float4*)&Gt[rr*64 + tc*4];
      float pav[8] = {pa0.x,pa0.y,pa0.z,pa0.w,pa1.x,pa1.y,pa1.z,pa1.w};
      float gbv[4] = {gb.x,gb.y,gb.z,gb.w};
      #pragma unroll
      for(int a=0;a<8;a++)
        #pragma unroll
        for(int b=0;b<4;b++) acc[a][b] += pav[a]*gbv[b];
    }
  }
  float* dst = part + ((size_t)blockIdx.y*BN + jbase)*Dd;
  #pragma unroll
  for(int a=0;a<8;a++){
    float4 v = make_float4(acc[a][0],acc[a][1],acc[a][2],acc[a][3]);
    *(float4*)&dst[(tr*8+a)*Dd + tc*4] = v;
  }
}

// ---------------- ef stage 2: reduce RC partials ----------------
__global__ void k_ef2(const float* __restrict__ part, float* __restrict__ ef){
  int i = blockIdx.x*256 + threadIdx.x;   // float4 index over BN*Dd/4
  float4 s = make_float4(0.f,0.f,0.f,0.f);
  #pragma unroll
  for(int c=0;c<RC;c++){
    float4 v = *(const float4*)&part[(size_t)c*BN*Dd + (size_t)i*4];
    s.x += v.x; s.y += v.y; s.z += v.z; s.w += v.w;
  }
  *(float4*)&ef[(size_t)i*4] = s;
}

// ---------------- normalized rows of g (8192 rows): gn = g / max(||g||,1e-12) ----------------
__global__ void k_gn(const float* __restrict__ x, float* __restrict__ gn){
  int r = blockIdx.x, d = threadIdx.x;
  float v = x[(size_t)r*Dd + d];
  float s = v*v;
  for(int o=32;o>0;o>>=1) s += __shfl_down(s, o, 64);
  s = __shfl(s, 0, 64);
  float inv = 1.0f/fmaxf(sqrtf(s), 1e-12f);
  gn[(size_t)r*Dd + d] = v*inv;
}

// ---------------- max-only cos2 GEMM: 16-col subtile maxima, NO S store ----------------
__global__ __launch_bounds__(256) void k_smax(const float* __restrict__ gn,
                                              float* __restrict__ Smax){
  __shared__ __align__(16) float A[64*128];    // [k][row]
  __shared__ __align__(16) float Bs[64*128];   // [k][col]
  int t = threadIdx.x;
  int ctile = blockIdx.x*128;
  int rtile = blockIdx.y*128;
  int q = t >> 4, m0 = t & 15;
  #pragma unroll
  for(int l=0;l<8;l++){
    int m = m0 + 16*l;
    float4 av = *(const float4*)&gn[(size_t)(rtile+m)*Dd + q*4];
    float4 bv = *(const float4*)&gn[(size_t)(ctile+m)*Dd + q*4];
    A[(q*4+0)*128 + m] = av.x; A[(q*4+1)*128 + m] = av.y;
    A[(q*4+2)*128 + m] = av.z; A[(q*4+3)*128 + m] = av.w;
    Bs[(q*4+0)*128 + m] = bv.x; Bs[(q*4+1)*128 + m] = bv.y;
    Bs[(q*4+2)*128 + m] = bv.z; Bs[(q*4+3)*128 + m] = bv.w;
  }
  __syncthreads();
  int tr = t >> 4;
  int tc = t & 15;
  float acc[8][8] = {};
  #pragma unroll 4
  for(int k=0;k<64;k++){
    float4 a0 = *(const float4*)&A[k*128 + tr*4];
    float4 a1 = *(const float4*)&A[k*128 + tr*4 + 64];
    float4 b0 = *(const float4*)&Bs[k*128 + tc*4];
    float4 b1 = *(const float4*)&Bs[k*128 + tc*4 + 64];
    float a[8] = {a0.x,a0.y,a0.z,a0.w,a1.x,a1.y,a1.z,a1.w};
    float b[8] = {b0.x,b0.y,b0.z,b0.w,b1.x,b1.y,b1.z,b1.w};
    #pragma unroll
    for(int i=0;i<8;i++)
      #pragma unroll
      for(int j=0;j<8;j++) acc[i][j] += a[i]*b[j];
  }
  #pragma unroll
  for(int i=0;i<8;i++){
    int r = rtile + tr*4 + (i&3) + (i>>2)*64;
    float mL = fmaxf(fmaxf(acc[i][0],acc[i][1]), fmaxf(acc[i][2],acc[i][3]));
    float mR = fmaxf(fmaxf(acc[i][4],acc[i][5]), fmaxf(acc[i][6],acc[i][7]));
    #pragma unroll
    for(int o=1;o<4;o<<=1){
      mL = fmaxf(mL, __shfl_xor(mL, o, 64));
      mR = fmaxf(mR, __shfl_xor(mR, o, 64));
    }
    if((tc & 3) == 0){
      Smax[(size_t)r*512 + blockIdx.x*8 + (tc>>2)]     = mL;
      Smax[(size_t)r*512 + blockIdx.x*8 + 4 + (tc>>2)] = mR;
    }
  }
}

// suffix-scan over 4096-bin hist: writes bc_bin/bc_need for rank-EXTRA.
#define HIST_PIVOT_SCAN()                                                   \
  do{                                                                       \
    unsigned lsum = 0u;                                                     \
    _Pragma("unroll")                                                       \
    for(int j=0;j<16;j++) lsum += hist[t*16 + j];                           \
    unsigned v = lsum;                                                      \
    _Pragma("unroll")                                                       \
    for(int o=1;o<64;o<<=1){                                                \
      unsigned u = (unsigned)__shfl_down((int)v, o, 64);                    \
      if(lane + o < 64) v += u;                                             \
    }                                                                       \
    if(lane == 0) wtot[wid] = v;                                            \
    __syncthreads();                                                        \
    unsigned cross = 0u;                                                    \
    _Pragma("unroll")                                                       \
    for(int w2=0;w2<4;w2++) if(w2 > wid) cross += wtot[w2];                 \
    unsigned Tinc = v + cross;                                              \
    unsigned above = Tinc - lsum;                                           \
    unsigned run = above;                                                   \
    _Pragma("unroll")                                                       \
    for(int b=15;b>=0;b--){                                                 \
      unsigned prev = run;                                                  \
      run += hist[t*16 + b];                                                \
      if(run >= EXTRA && prev < EXTRA){ bc_bin = (unsigned)(t*16 + b); bc_need = EXTRA - prev; } \
    }                                                                       \
  }while(0)

// ---------------- exact per-row top-25 by sparse recompute ----------------
// Stage 1: histogram the 512 subtile maxima; pivot bin where cumulative-from-
// top reaches 25. Threshold = pivot-bin FLOOR <= L (exact 25th max) <= V25,
// so subtiles with bin(max) >= pivot cover every true top-25 value. Stage 2:
// wave-parallel recompute of candidate columns (coalesced 64-lane loads +
// shuffle reduce), histogram pivot for row rank-25, emit. Cap overflow ->
// flag for k_fix.
__global__ __launch_bounds__(256) void k_sel(const float* __restrict__ gn,
                                             const float* __restrict__ Smax,
                                             float* __restrict__ topv2, int* __restrict__ topi2,
                                             int* __restrict__ flag){
  __shared__ unsigned hist[4096];
  __shared__ unsigned wtot[4];
  __shared__ unsigned bc_bin, bc_need, bc_cnt, bc_c;
  __shared__ unsigned sub[SUBCAP];
  __shared__ unsigned nsub, ovf;
  __shared__ unsigned candV[SUBCAP*16];
  __shared__ unsigned short candC[SUBCAP*16];
  __shared__ unsigned p2E[PV2CAP];
  __shared__ unsigned short p2C[PV2CAP];
  int r = blockIdx.x, t = threadIdx.x;
  int lane = t & 63, wid = t >> 6;
  float m0 = Smax[(size_t)r*512 + t];
  float m1 = Smax[(size_t)r*512 + 256 + t];
  #pragma unroll
  for(int j=0;j<16;j++) hist[t*16 + j] = 0u;
  if(t==0){ nsub = 0u; ovf = 0u; bc_c = 0u; bc_cnt = 0u; }
  __syncthreads();
  // ---- stage 1: pivot bin over subtile maxima ----
  atomicAdd(&hist[fenc(m0) >> 20], 1u);
  atomicAdd(&hist[fenc(m1) >> 20], 1u);
  __syncthreads();
  HIST_PIVOT_SCAN();
  __syncthreads();
  unsigned pivot1 = bc_bin;
  if((fenc(m0) >> 20) >= pivot1){
    unsigned k = atomicAdd(&nsub, 1u);
    if(k < SUBCAP) sub[k] = (unsigned)t; else ovf = 1u;
  }
  if((fenc(m1) >> 20) >= pivot1){
    unsigned k = atomicAdd(&nsub, 1u);
    if(k < SUBCAP) sub[k] = (unsigned)(256 + t); else ovf = 1u;
  }
  __syncthreads();
  if(ovf){ if(t==0) flag[r] = 1; return; }
  // ---- stage 2: wave-parallel recompute + pivot selection ----
  #pragma unroll
  for(int j=0;j<16;j++) hist[t*16 + j] = 0u;
  __syncthreads();
  unsigned ns = nsub;
  unsigned c = ns*16;
  float vl = gn[(size_t)r*Dd + lane];
  for(unsigned i = wid; i < c; i += 4){
    int col = (int)sub[i>>4]*16 + (int)(i & 15);
    float p = gn[(size_t)col*Dd + lane] * vl;
    #pragma unroll
    for(int o=32;o>0;o>>=1) p += __shfl_down(p, o, 64);
    if(lane == 0){
      unsigned e = fenc(p);
      candV[i] = e; candC[i] = (unsigned short)col;
      atomicAdd(&hist[e >> 20], 1u);
    }
  }
  __syncthreads();
  HIST_PIVOT_SCAN();
  __syncthreads();
  unsigned pivot2 = bc_bin, need2 = bc_need;
  for(unsigned i=t; i<c; i+=256){
    unsigned e = candV[i];
    unsigned bin = e >> 20;
    if(bin > pivot2){
      unsigned s = atomicAdd(&bc_cnt, 1u);
      topv2[r*EXTRA + s] = fdec(e);
      topi2[r*EXTRA + s] = (int)candC[i];
    } else if(bin == pivot2){
      unsigned k = atomicAdd(&bc_c, 1u);
      if(k < PV2CAP){ p2E[k] = e; p2C[k] = candC[i]; } else ovf = 1u;
    }
  }
  __syncthreads();
  if(ovf){ if(t==0) flag[r] = 1; return; }   // k_fix rewrites all 25 slots
  unsigned p2 = bc_c;
  for(unsigned i=t; i<p2; i+=256){
    unsigned ei = p2E[i]; unsigned ci = p2C[i];
    unsigned rank = 0;
    for(unsigned j=0;j<p2;j++){
      rank += (p2E[j] > ei) || (p2E[j] == ei && p2C[j] < ci);
    }
    if(rank < need2){
      unsigned s = atomicAdd(&bc_cnt, 1u);
      topv2[r*EXTRA + s] = fdec(ei);
      topi2[r*EXTRA + s] = (int)ci;
    }
  }
}

// ---------------- rare fallback: exact full-row selection (coalesced) ----------------
// Wave-parallel dots (lane = element d; one column per wave per iter, 256 B
// contiguous loads + shuffle reduce) fill sdot, then the proven histogram
// pivot machinery selects exactly 25.
__global__ __launch_bounds__(256) void k_fix(const float* __restrict__ gn,
                                             const int* __restrict__ flag,
                                             float* __restrict__ topv2, int* __restrict__ topi2){
  int r = blockIdx.x;
  if(flag[r] == 0) return;
  __shared__ float sdot[TBN];
  __shared__ unsigned hist[4096];
  __shared__ unsigned wtot[4];
  __shared__ unsigned candE[CAND_CAP];
  __shared__ unsigned short candC[CAND_CAP];
  __shared__ unsigned bc_bin, bc_need, bc_cnt, bc_c;
  int t = threadIdx.x;
  int lane = t & 63, wid = t >> 6;
  float vl = gn[(size_t)r*Dd + lane];
  for(int cix = wid; cix < TBN; cix += 4){
    float p = gn[(size_t)cix*Dd + lane] * vl;
    #pragma unroll
    for(int o=32;o>0;o>>=1) p += __shfl_down(p, o, 64);
    if(lane == 0) sdot[cix] = p;
  }
  __syncthreads();
  int col0 = t*32;
  unsigned enc[32];
  #pragma unroll
  for(int j=0;j<32;j++) enc[j] = fenc(sdot[col0 + j]);
  #pragma unroll
  for(int j=0;j<16;j++) hist[t*16 + j] = 0u;
  __syncthreads();
  #pragma unroll
  for(int j=0;j<32;j++) atomicAdd(&hist[enc[j] >> 20], 1u);
  __syncthreads();
  HIST_PIVOT_SCAN();
  if(t==0){ bc_cnt = 0u; bc_c = 0u; }
  __syncthreads();
  unsigned pivotBin = bc_bin, needIn = bc_need;
  #pragma unroll
  for(int j=0;j<32;j++){
    unsigned e = enc[j];
    unsigned bin = e >> 20;
    if(bin > pivotBin){
      unsigned s = atomicAdd(&bc_cnt, 1u);
      topv2[r*EXTRA + s] = fdec(e);
      topi2[r*EXTRA + s] = col0 + j;
    } else if(bin == pivotBin){
      unsigned ci = atomicAdd(&bc_c, 1u);
      if(ci < CAND_CAP){ candE[ci] = e; candC[ci] = (unsigned short)(col0 + j); }
    }
  }
  __syncthreads();
  unsigned c = bc_c;
  if(c <= CAND_CAP){
    for(unsigned i=t; i<c; i+=256){
      unsigned ei = candE[i]; unsigned coli = candC[i];
      unsigned rank = 0;
      for(unsigned j2=0;j2<c;j2++){
        unsigned ej = candE[j2];
        rank += (ej > ei) || (ej == ei && candC[j2] < coli);
      }
      if(rank < needIn){
        unsigned s = atomicAdd(&bc_cnt, 1u);
        topv2[r*EXTRA + s] = fdec(ei);
        topi2[r*EXTRA + s] = (int)coli;
      }
    }
  } else {
    unsigned* h256  = hist;
    unsigned* scanb = hist + 1024;
    unsigned prefix = pivotBin;
    unsigned need = needIn;
    const int shifts[3] = {12, 4, 0};
    const unsigned masks[3] = {255u, 255u, 15u};
    const int nbins[3] = {256, 256, 16};
    for(int p=0;p<3;p++){
      int sh = shifts[p]; unsigned mk = masks[p]; int nb = nbins[p];
      if(t < nb) h256[t] = 0u;
      __syncthreads();
      #pragma unroll
      for(int j=0;j<32;j++){
        unsigned e = enc[j];
        int pshift = (p==0)? 20 : (p==1? 12 : 4);
        if((e >> pshift) == prefix) atomicAdd(&h256[(e>>sh)&mk], 1u);
      }
      __syncthreads();
      unsigned vv = (t < nb) ? h256[t] : 0u;
      for(int o=1;o<nb;o<<=1){
        if(t < nb) scanb[t] = vv;
        __syncthreads();
        if(t < nb && t+o < nb) vv += scanb[t+o];
        __syncthreads();
      }
      if(t < nb) scanb[t] = vv;
      __syncthreads();
      if(t < nb){
        unsigned nxt = (t < nb-1) ? scanb[t+1] : 0u;
        if(vv >= need && nxt < need){ bc_bin = (prefix << ((p==2)?4:8)) | (unsigned)t; bc_need = need - nxt; }
      }
      __syncthreads();
      prefix = bc_bin; need = bc_need;
      __syncthreads();
    }
    unsigned pivotEnc = prefix;
    unsigned needTies = need;
    unsigned tie_local = 0u;
    #pragma unroll
    for(int j=0;j<32;j++){
      unsigned e = enc[j];
      if((e >> 20) == pivotBin){
        if(e > pivotEnc){
          unsigned s = atomicAdd(&bc_cnt, 1u);
          topv2[r*EXTRA + s] = fdec(e);
          topi2[r*EXTRA + s] = col0 + j;
        } else if(e == pivotEnc) tie_local++;
      }
    }
    unsigned iv = tie_local;
    for(int o=1;o<256;o<<=1){
      scanb[t] = iv; __syncthreads();
      if(t >= o) iv += scanb[t-o];
      __syncthreads();
    }
    unsigned rank = iv - tie_local;
    #pragma unroll
    for(int j=0;j<32;j++){
      unsigned e = enc[j];
      if(e == pivotEnc && (e >> 20) == pivotBin){
        if(rank < needTies){
          unsigned s = atomicAdd(&bc_cnt, 1u);
          topv2[r*EXTRA + s] = fdec(e);
          topi2[r*EXTRA + s] = col0 + j;
        }
        rank++;
      }
    }
  }
}

// ---------------- h2 = g@W2, attention logits (rows < BN only) ----------------
__global__ void k_h2(const float* __restrict__ g, const float* __restrict__ W2,
                     const float* __restrict__ ai2w, const float* __restrict__ aj2w,
                     float* __restrict__ h2, float* __restrict__ a2i, float* __restrict__ a2j){
  int r = blockIdx.x, d = threadIdx.x;
  __shared__ float gr[Dd];
  gr[d] = g[(size_t)r*Dd + d];
  __syncthreads();
  float hv = 0.f;
  #pragma unroll
  for(int k=0;k<Dd;k++) hv += gr[k]*W2[k*Dd + d];
  h2[(size_t)r*Dd + d] = hv;
  float a = hv*ai2w[d];
  float b = hv*aj2w[d];
  for(int o=32;o>0;o>>=1){ a += __shfl_down(a,o,64); b += __shfl_down(b,o,64); }
  if(d==0){ a2i[r]=a; a2j[r]=b; }
}

// ---------------- layer-2 edge scores + segment max ----------------
__global__ void k_s2(const float* __restrict__ a2i, const float* __restrict__ a2j,
                     const float* __restrict__ topv2, const int* __restrict__ topi2,
                     float* __restrict__ s2, unsigned int* __restrict__ segmax){
  int e = blockIdx.x*256 + threadIdx.x;
  if(e >= BN*EXTRA) return;
  int r = e/EXTRA;
  int dst = topi2[e];
  if(dst >= BN) return;
  float sc = a2i[dst] + a2j[r];
  sc = sc >= 0.f ? sc : SLOPE*sc;
  sc *= topv2[e];
  s2[e] = sc;
  atomicMax(&segmax[dst], fenc(sc));
}

// ---------------- exp + segment sum ----------------
__global__ void k_e2(const float* __restrict__ s2, const int* __restrict__ topi2,
                     const unsigned int* __restrict__ segmax,
                     float* __restrict__ e2, float* __restrict__ ssum){
  int e = blockIdx.x*256 + threadIdx.x;
  if(e >= BN*EXTRA) return;
  int dst = topi2[e];
  if(dst >= BN) return;
  float m = fdec(segmax[dst]);
  float v = expf(s2[e] - m);
  e2[e] = v;
  atomicAdd(&ssum[dst], v);
}

// ---------------- weighted scatter into agg2 ----------------
__global__ void k_scat(const float* __restrict__ e2, const float* __restrict__ ssum,
                       const int* __restrict__ topi2, const float* __restrict__ h2,
                       float* __restrict__ agg2){
  int idx = blockIdx.x*256 + threadIdx.x;
  int e = idx >> 6, d = idx & 63;
  int dst = topi2[e];
  if(dst >= BN) return;
  int src = e/EXTRA;
  float alpha = e2[e]/fmaxf(ssum[dst], 1e-12f);
  atomicAdd(&agg2[(size_t)dst*Dd + d], alpha*h2[(size_t)src*Dd + d]);
}

// ---------------- head stats over x3 = relu(agg2+bias2)*emb ----------------
__global__ void k_headstats(const float* __restrict__ agg2, const float* __restrict__ bias2,
                            const float* __restrict__ emb, float* __restrict__ mu2, float* __restrict__ var2){
  int c = blockIdx.x, t = threadIdx.x;
  float bc = bias2[c];
  float s = 0.f, s2 = 0.f;
  for(int r=t; r<BN; r+=256){
    float v = fmaxf(agg2[(size_t)r*Dd + c] + bc, 0.f) * emb[(r & (Nn-1))*Dd + c];
    s += v; s2 += v*v;
  }
  __shared__ float ls[256], ls2[256];
  ls[t]=s; ls2[t]=s2; __syncthreads();
  for(int o=128;o>0;o>>=1){
    if(t<o){ ls[t]+=ls[t+o]; ls2[t]+=ls2[t+o]; }
    __syncthreads();
  }
  if(t==0){ float m=ls[0]/BN; mu2[c]=m; var2[c]=ls2[0]/BN - m*m; }
}

// ---------------- final: BN + relu + Linear(D,1) ----------------
__global__ void k_out(const float* __restrict__ agg2, const float* __restrict__ bias2,
                      const float* __restrict__ emb, const float* __restrict__ mu2,
                      const float* __restrict__ var2, const float* __restrict__ gO,
                      const float* __restrict__ bO, const float* __restrict__ Wout,
                      const float* __restrict__ bout, float* __restrict__ out){
  int r = blockIdx.x, d = threadIdx.x;
  float v = fmaxf(agg2[(size_t)r*Dd + d] + bias2[d], 0.f) * emb[(r & (Nn-1))*Dd + d];
  float y = gO[d]*(v - mu2[d])/sqrtf(var2[d]+EPS) + bO[d];
  y = fmaxf(y, 0.f)*Wout[d];
  for(int o=32;o>0;o>>=1) y += __shfl_down(y, o, 64);
  if(d==0) out[r] = y + bout[0];
}

extern "C" void kernel_launch(void* const* d_in, const int* in_sizes, int n_in,
                              void* d_out, int out_size, void* d_ws, size_t ws_size,
                              hipStream_t stream){
  const float* data  = (const float*)d_in[0];
  const float* emb   = (const float*)d_in[1];
  const float* W1    = (const float*)d_in[2];
  const float* ai1   = (const float*)d_in[3];
  const float* aj1   = (const float*)d_in[4];
  const float* bias1 = (const float*)d_in[5];
  const float* bn1g  = (const float*)d_in[6];
  const float* bn1b  = (const float*)d_in[7];
  const float* P     = (const float*)d_in[8];
  const float* W2    = (const float*)d_in[9];
  const float* ai2w  = (const float*)d_in[10];
  const float* aj2w  = (const float*)d_in[11];
  const float* bias2 = (const float*)d_in[12];
  const float* bnOg  = (const float*)d_in[13];
  const float* bnOb  = (const float*)d_in[14];
  const float* Wout  = (const float*)d_in[15];
  const float* bout  = (const float*)d_in[16];
  float* out = (float*)d_out;

  char* w = (char*)d_ws;
  auto alloc = [&](size_t nbytes)->char*{
    char* p = w; w += (nbytes + 255) & ~(size_t)255; return p;
  };
  float* norms1 = (float*)alloc(Nn*4);
  float* topv1  = (float*)alloc(Nn*TOPK*4);
  int*   topi1  = (int*)  alloc(Nn*TOPK*4);
  float* h      = (float*)alloc((size_t)BN*Dd*4);
  float* si     = (float*)alloc(BN*4);
  float* sj     = (float*)alloc(BN*4);
  float* agg1   = (float*)alloc((size_t)BN*Dd*4);
  float* mu1    = (float*)alloc(Dd*4);
  float* var1   = (float*)alloc(Dd*4);
  float* g      = (float*)alloc((size_t)TBN*Dd*4);
  float* gn     = (float*)alloc((size_t)TBN*Dd*4);
  float* topv2  = (float*)alloc((size_t)BN*EXTRA*4);
  int*   topi2  = (int*)  alloc((size_t)BN*EXTRA*4);
  float* h2     = (float*)alloc((size_t)TBN*Dd*4);
  float* a2i    = (float*)alloc(TBN*4);
  float* a2j    = (float*)alloc(TBN*4);
  float* s2     = (float*)alloc((size_t)BN*EXTRA*4);
  float* e2     = (float*)alloc((size_t)BN*EXTRA*4);
  // contiguous zero region: agg2 | ssum | segmax | selflag
  float* zblock = (float*)alloc(((size_t)TBN*Dd + TBN + TBN + BN)*4);
  float* agg2   = zblock;
  float* ssum   = zblock + (size_t)TBN*Dd;
  unsigned int* segmax = (unsigned int*)(ssum + TBN);
  int* flagB    = (int*)(segmax + TBN);
  float* mu2    = (float*)alloc(Dd*4);
  float* var2   = (float*)alloc(Dd*4);
  float* efpart = (float*)alloc((size_t)RC*BN*Dd*4);   // 16 MB split-K partials
  float* SmaxB  = (float*)alloc((size_t)BN*512*4);     // per-row 16-col subtile maxima (8 MB)

  // ---- layer 1 ----
  k_emb_norm<<<Nn, 64, 0, stream>>>(emb, norms1);
  k_emb_topk<<<Nn, Nn, 0, stream>>>(emb, norms1, topv1, topi1);
  k_h1<<<BN, 64, 0, stream>>>(data, emb, W1, ai1, aj1, h, si, sj);
  k_agg1<<<BN, 64, 0, stream>>>(h, si, sj, topv1, topi1, bias1, agg1);
  k_colstats<<<Dd, 256, 0, stream>>>(agg1, mu1, var1);
  k_bnrelu1<<<(BN*Dd)/256, 256, 0, stream>>>(agg1, mu1, var1, bn1g, bn1b, g);

  // ---- ef = P^T gcn : split-K, no atomics ----
  k_ef1<<<dim3(BN/128, RC), 256, 0, stream>>>(P, g, efpart);
  k_ef2<<<(BN*Dd/4)/256, 256, 0, stream>>>(efpart, g + (size_t)BN*Dd);

  // ---- zero agg2 | ssum | segmax | flag early ----
  k_zero<<<((TBN*Dd + 2*TBN + BN) + 255)/256, 256, 0, stream>>>(zblock, TBN*Dd + 2*TBN + BN);

  // ---- cos2 top-25: max-only GEMM + histogram-pivot sparse recompute (no S) ----
  k_gn<<<TBN, 64, 0, stream>>>(g, gn);
  k_smax<<<dim3(TBN/128, BN/128), 256, 0, stream>>>(gn, SmaxB);
  k_sel<<<BN, 256, 0, stream>>>(gn, SmaxB, topv2, topi2, flagB);
  k_fix<<<BN, 256, 0, stream>>>(gn, flagB, topv2, topi2);

  // ---- layer 2 ----
  k_h2<<<BN, 64, 0, stream>>>(g, W2, ai2w, aj2w, h2, a2i, a2j);
  k_s2<<<(BN*EXTRA + 255)/256, 256, 0, stream>>>(a2i, a2j, topv2, topi2, s2, segmax);
  k_e2<<<(BN*EXTRA + 255)/256, 256, 0, stream>>>(s2, topi2, segmax, e2, ssum);
  k_scat<<<(BN*EXTRA*Dd)/256, 256, 0, stream>>>(e2, ssum, topi2, h2, agg2);

  // ---- head ----
  k_headstats<<<Dd, 256, 0, stream>>>(agg2, bias2, emb, mu2, var2);
  k_out<<<BN, 64, 0, stream>>>(agg2, bias2, emb, mu2, var2, bnOg, bnOb, Wout, bout, out);
}

// Round 14
// 355.680 us; speedup vs baseline: 2.3501x; 2.3501x over previous
//
#include <hip/hip_runtime.h>
#include <hip/hip_bf16.h>
#include <math.h>

#define DEV __device__ __forceinline__

constexpr int Bb   = 32;
constexpr int Nn   = 128;
constexpr int Ff   = 10;
constexpr int Dd   = 64;
constexpr int TOPK = 20;
constexpr int EXTRA= 25;
constexpr int BN   = 4096;   // B*N
constexpr int TBN  = 8192;   // 2*BN
constexpr int RC   = 16;     // r-chunks for split-K ef
constexpr int CAND_CAP = 1024;
constexpr float EPS   = 1e-5f;
constexpr float SLOPE = 0.2f;

// order-preserving float<->uint encoding (monotone: a<b  <=> fenc(a)<fenc(b))
DEV unsigned int fenc(float f){
  unsigned int b = __float_as_uint(f);
  return (b & 0x80000000u) ? ~b : (b | 0x80000000u);
}
DEV float fdec(unsigned int u){
  unsigned int b = (u & 0x80000000u) ? (u & 0x7FFFFFFFu) : ~u;
  return __uint_as_float(b);
}

// ---------------- generic zero ----------------
__global__ void k_zero(float* __restrict__ p, int n){
  int i = blockIdx.x*256 + threadIdx.x;
  if(i < n) p[i] = 0.f;
}

// ---------------- emb row norms ----------------
__global__ void k_emb_norm(const float* __restrict__ emb, float* __restrict__ norms){
  int i = blockIdx.x, d = threadIdx.x;
  float v = emb[i*Dd + d];
  float s = v*v;
  for(int o=32;o>0;o>>=1) s += __shfl_down(s, o, 64);
  if(d==0) norms[i] = fmaxf(sqrtf(s), 1e-12f);
}

// ---------------- emb cosine + top-20 per row: single-pass rank select ----------------
// rank = #{j : v_j > v_t or (v_j == v_t and j < t)} gives the exact ordered
// top-20 ((value desc, index asc) — identical to the iterative-max tie rule
// and jax.lax.top_k stability) with no serial selection loop.
__global__ void k_emb_topk(const float* __restrict__ emb, const float* __restrict__ norms,
                           float* __restrict__ topv, int* __restrict__ topi){
  __shared__ float se[Dd];
  __shared__ float sc[Nn];
  int i = blockIdx.x, t = threadIdx.x;
  if(t < Dd) se[t] = emb[i*Dd + t];
  __syncthreads();
  float dot = 0.f;
  for(int d=0; d<Dd; d++) dot += se[d]*emb[t*Dd + d];
  float v = dot/(norms[i]*norms[t]);
  sc[t] = v;
  __syncthreads();
  int rank = 0;
  for(int j=0; j<Nn; j++){
    float vj = sc[j];
    rank += (vj > v) || (vj == v && j < t);
  }
  if(rank < TOPK){
    topv[i*TOPK + rank] = v;
    topi[i*TOPK + rank] = t;
  }
}

// ---------------- h = x@W1, si/sj attention logits ----------------
__global__ void k_h1(const float* __restrict__ data, const float* __restrict__ emb,
                     const float* __restrict__ W1, const float* __restrict__ ai1,
                     const float* __restrict__ aj1,
                     float* __restrict__ h, float* __restrict__ si, float* __restrict__ sj){
  int r = blockIdx.x, d = threadIdx.x;
  int node = r & (Nn-1);
  __shared__ float xr[Ff];
  if(d < Ff) xr[d] = data[r*Ff + d];
  __syncthreads();
  float hv = 0.f;
  #pragma unroll
  for(int f=0; f<Ff; f++) hv += xr[f]*W1[f*Dd + d];
  h[r*Dd + d] = hv;
  float e = emb[node*Dd + d];
  float a = hv*ai1[d] + e*ai1[Dd + d];
  float b = hv*aj1[d] + e*aj1[Dd + d];
  for(int o=32;o>0;o>>=1){ a += __shfl_down(a,o,64); b += __shfl_down(b,o,64); }
  if(d==0){ si[r] = a; sj[r] = b; }
}

// ---------------- layer-1 segment softmax + aggregation ----------------
__global__ void k_agg1(const float* __restrict__ h, const float* __restrict__ si,
                       const float* __restrict__ sj, const float* __restrict__ topv,
                       const int* __restrict__ topi, const float* __restrict__ bias1,
                       float* __restrict__ agg){
  int r = blockIdx.x, d = threadIdx.x;
  int b = r >> 7, node = r & (Nn-1);
  __shared__ float sal[TOPK];
  __shared__ int   ssrc[TOPK];
  if(d < TOPK){
    int s = b*Nn + topi[node*TOPK + d];
    float sc = si[r] + sj[s];
    sc = sc >= 0.f ? sc : SLOPE*sc;
    sal[d] = sc * topv[node*TOPK + d];
    ssrc[d] = s;
  }
  __syncthreads();
  float m = -INFINITY;
  #pragma unroll
  for(int k=0;k<TOPK;k++) m = fmaxf(m, sal[k]);
  float al[TOPK]; float ssum = 0.f;
  #pragma unroll
  for(int k=0;k<TOPK;k++){ al[k] = expf(sal[k]-m); ssum += al[k]; }
  float inv = 1.0f/fmaxf(ssum, 1e-12f);
  float acc = 0.f;
  #pragma unroll
  for(int k=0;k<TOPK;k++) acc += al[k]*inv*h[ssrc[k]*Dd + d];
  agg[r*Dd + d] = acc + bias1[d];
}

// ---------------- per-channel stats over BN rows (agg1) ----------------
__global__ void k_colstats(const float* __restrict__ x, float* __restrict__ mu, float* __restrict__ var){
  int c = blockIdx.x, t = threadIdx.x;
  float s = 0.f, s2 = 0.f;
  for(int r=t; r<BN; r+=256){ float v = x[r*Dd + c]; s += v; s2 += v*v; }
  __shared__ float ls[256], ls2[256];
  ls[t]=s; ls2[t]=s2; __syncthreads();
  for(int o=128;o>0;o>>=1){
    if(t<o){ ls[t]+=ls[t+o]; ls2[t]+=ls2[t+o]; }
    __syncthreads();
  }
  if(t==0){ float m = ls[0]/BN; mu[c]=m; var[c]=ls2[0]/BN - m*m; }
}

// ---------------- BN1 + relu -> g[0:BN] ----------------
__global__ void k_bnrelu1(const float* __restrict__ agg, const float* __restrict__ mu,
                          const float* __restrict__ var, const float* __restrict__ gamma,
                          const float* __restrict__ beta, float* __restrict__ g){
  int idx = blockIdx.x*256 + threadIdx.x;
  int c = idx & (Dd-1);
  float v = agg[idx];
  float y = gamma[c]*(v - mu[c])/sqrtf(var[c]+EPS) + beta[c];
  g[idx] = fmaxf(y, 0.f);
}

// ---------------- ef stage 1: partial P^T @ gcn tiles, non-atomic ----------------
// 128-wide j-tile, acc[8][4]/thread: 1.5 B LDS read per FMA (was 2.0),
// 2x FMA per staged byte. Fragment reads bank-conflict-free
// (Pt broadcast at banks {0,8,16,24}; Gt 2-way = free).
__global__ __launch_bounds__(256) void k_ef1(const float* __restrict__ P, const float* __restrict__ gcn,
                                             float* __restrict__ part){
  __shared__ float Pt[16*128];
  __shared__ float Gt[16*64];
  int t = threadIdx.x;
  int jbase = blockIdx.x*128;
  int r0 = blockIdx.y*256;
  int row = t >> 4, col4 = (t & 15)*4;
  int tr = t >> 4, tc = t & 15;
  float acc[8][4] = {};
  for(int step=0; step<16; step++){
    int r = r0 + step*16;
    float4 pv0 = *(const float4*)&P[(size_t)(r+row)*BN + jbase + col4];
    float4 pv1 = *(const float4*)&P[(size_t)(r+row)*BN + jbase + col4 + 64];
    float4 gv  = *(const float4*)&gcn[(r+row)*Dd + col4];
    __syncthreads();
    *(float4*)&Pt[row*128 + col4]      = pv0;
    *(float4*)&Pt[row*128 + col4 + 64] = pv1;
    *(float4*)&Gt[row*64 + col4] = gv;
    __syncthreads();
    #pragma unroll
    for(int rr=0; rr<16; rr++){
      float4 pa0 = *(float4*)&Pt[rr*128 + tr*8];
      float4 pa1 = *(float4*)&Pt[rr*128 + tr*8 + 4];
      float4 gb  = *(float4*)&Gt[rr*64 + tc*4];
      float pav[8] = {pa0.x,pa0.y,pa0.z,pa0.w,pa1.x,pa1.y,pa1.z,pa1.w};
      float gbv[4] = {gb.x,gb.y,gb.z,gb.w};
      #pragma unroll
      for(int a=0;a<8;a++)
        #pragma unroll
        for(int b=0;b<4;b++) acc[a][b] += pav[a]*gbv[b];
    }
  }
  float* dst = part + ((size_t)blockIdx.y*BN + jbase)*Dd;
  #pragma unroll
  for(int a=0;a<8;a++){
    float4 v = make_float4(acc[a][0],acc[a][1],acc[a][2],acc[a][3]);
    *(float4*)&dst[(tr*8+a)*Dd + tc*4] = v;
  }
}

// ---------------- ef stage 2: reduce RC partials ----------------
__global__ void k_ef2(const float* __restrict__ part, float* __restrict__ ef){
  int i = blockIdx.x*256 + threadIdx.x;   // float4 index over BN*Dd/4
  float4 s = make_float4(0.f,0.f,0.f,0.f);
  #pragma unroll
  for(int c=0;c<RC;c++){
    float4 v = *(const float4*)&part[(size_t)c*BN*Dd + (size_t)i*4];
    s.x += v.x; s.y += v.y; s.z += v.z; s.w += v.w;
  }
  *(float4*)&ef[(size_t)i*4] = s;
}

// ---------------- normalized rows of g (8192 rows): gn = g / max(||g||,1e-12) ----------------
__global__ void k_gn(const float* __restrict__ x, float* __restrict__ gn){
  int r = blockIdx.x, d = threadIdx.x;
  float v = x[(size_t)r*Dd + d];
  float s = v*v;
  for(int o=32;o>0;o>>=1) s += __shfl_down(s, o, 64);
  s = __shfl(s, 0, 64);
  float inv = 1.0f/fmaxf(sqrtf(s), 1e-12f);
  gn[(size_t)r*Dd + d] = v*inv;
}

// ---------------- S chunk GEMM (fp32+LDS, measured 58-63us) + 16-col Smax ----------------
// 128x128 tile/block, 256 threads, per-thread 2x2 blocks of 4x4 so all LDS
// fragment reads are ds_read_b128. K=64 staged once. Emits per-row 16-col
// SUBTILE maxima (8 per 128-col block, 512/row) for k_radix's fine-grain
// exact tile-skip.
__global__ __launch_bounds__(256) void k_sgemm(const float* __restrict__ gn,
                                               int rbase, float* __restrict__ S,
                                               float* __restrict__ Smax){
  __shared__ __align__(16) float A[64*128];    // [k][row]
  __shared__ __align__(16) float Bs[64*128];   // [k][col]
  int t = threadIdx.x;
  int ctile = blockIdx.x*128;
  int rtile = rbase + blockIdx.y*128;
  int q = t >> 4, m0 = t & 15;
  #pragma unroll
  for(int l=0;l<8;l++){
    int m = m0 + 16*l;
    float4 av = *(const float4*)&gn[(size_t)(rtile+m)*Dd + q*4];
    float4 bv = *(const float4*)&gn[(size_t)(ctile+m)*Dd + q*4];
    A[(q*4+0)*128 + m] = av.x; A[(q*4+1)*128 + m] = av.y;
    A[(q*4+2)*128 + m] = av.z; A[(q*4+3)*128 + m] = av.w;
    Bs[(q*4+0)*128 + m] = bv.x; Bs[(q*4+1)*128 + m] = bv.y;
    Bs[(q*4+2)*128 + m] = bv.z; Bs[(q*4+3)*128 + m] = bv.w;
  }
  __syncthreads();
  int tr = t >> 4;          // 0..15 -> row block
  int tc = t & 15;          // 0..15 -> col block
  float acc[8][8] = {};
  #pragma unroll 4
  for(int k=0;k<64;k++){
    float4 a0 = *(const float4*)&A[k*128 + tr*4];
    float4 a1 = *(const float4*)&A[k*128 + tr*4 + 64];
    float4 b0 = *(const float4*)&Bs[k*128 + tc*4];
    float4 b1 = *(const float4*)&Bs[k*128 + tc*4 + 64];
    float a[8] = {a0.x,a0.y,a0.z,a0.w,a1.x,a1.y,a1.z,a1.w};
    float b[8] = {b0.x,b0.y,b0.z,b0.w,b1.x,b1.y,b1.z,b1.w};
    #pragma unroll
    for(int i=0;i<8;i++)
      #pragma unroll
      for(int j=0;j<8;j++) acc[i][j] += a[i]*b[j];
  }
  int rloc = blockIdx.y*128;
  // Per row, 16-col subtile maxima. Thread's acc[i][0..3] = cols tc*4..+3
  // (left 64), acc[i][4..7] = cols 64+tc*4..+3. A 16-col subtile = 4
  // adjacent tc -> local max of 4 + xor-shuffle o=1,2 within the tc%4
  // group; (tc&3)==0 lanes write subtile (tc>>2) / 4+(tc>>2).
  #pragma unroll
  for(int i=0;i<8;i++){
    int rl = tr*4 + (i&3) + (i>>2)*64;
    int r  = rloc + rl;
    float mL = fmaxf(fmaxf(acc[i][0],acc[i][1]), fmaxf(acc[i][2],acc[i][3]));
    float mR = fmaxf(fmaxf(acc[i][4],acc[i][5]), fmaxf(acc[i][6],acc[i][7]));
    #pragma unroll
    for(int o=1;o<4;o<<=1){
      mL = fmaxf(mL, __shfl_xor(mL, o, 64));
      mR = fmaxf(mR, __shfl_xor(mR, o, 64));
    }
    if((tc & 3) == 0){
      Smax[(size_t)r*512 + blockIdx.x*8 + (tc>>2)]     = mL;
      Smax[(size_t)r*512 + blockIdx.x*8 + 4 + (tc>>2)] = mR;
    }
    float4 v0 = make_float4(acc[i][0],acc[i][1],acc[i][2],acc[i][3]);
    float4 v1 = make_float4(acc[i][4],acc[i][5],acc[i][6],acc[i][7]);
    *(float4*)&S[(size_t)r*TBN + ctile + tc*4]      = v0;
    *(float4*)&S[(size_t)r*TBN + ctile + tc*4 + 64] = v1;
  }
}

// ---------------- exact top-25 per row with 16-col tile-skip ----------------
// L = 25th-largest of the row's 64 (128-col) tile maxima is a lower bound on
// the 25th value (those top-25 maxima ARE 25 row values >= L). Skip any
// 16-col subtile whose max < L: its values are < L <= V25 and cannot enter
// the top-25 or perturb pivot counts. Skipped slots encode as 0u (bin 0);
// real cosines have fenc bin >= 1031 -> exact.
__global__ __launch_bounds__(256) void k_radix(const float* __restrict__ S,
                                               const float* __restrict__ Smax,
                                               int rbase,
                                               float* __restrict__ topv2, int* __restrict__ topi2){
  __shared__ unsigned hist[4096];
  __shared__ unsigned wtot[4];
  __shared__ unsigned candE[CAND_CAP];
  __shared__ unsigned short candC[CAND_CAP];
  __shared__ unsigned bc_bin, bc_need, bc_cnt, bc_c;
  __shared__ float st16[512];
  __shared__ float stmax[64];
  __shared__ float sLsh;
  int t = threadIdx.x;
  int lane = t & 63, wid = t >> 6;
  int r = blockIdx.x;
  const float* src = S + (size_t)r*TBN;
  int col0 = t*32;

  st16[t]       = Smax[(size_t)r*512 + t];
  st16[256 + t] = Smax[(size_t)r*512 + 256 + t];
  #pragma unroll
  for(int j=0;j<16;j++) hist[t*16 + j] = 0u;
  if(t==0){ bc_cnt = 0u; bc_c = 0u; }
  __syncthreads();
  if(t < 64){
    float m = st16[t*8];
    #pragma unroll
    for(int k=1;k<8;k++) m = fmaxf(m, st16[t*8 + k]);
    stmax[t] = m;
  }
  __syncthreads();
  if(t < 64){
    float mi = stmax[t];
    int cnt = 0;
    for(int j=0;j<64;j++){
      float mj = stmax[j];
      cnt += (mj > mi) || (mj == mi && j < t);
    }
    if(cnt == 24) sLsh = mi;
  }
  __syncthreads();
  float L = sLsh;
  // thread t covers cols [t*32, t*32+32) = subtiles 2t, 2t+1
  bool skip = fmaxf(st16[t*2], st16[t*2+1]) < L;

  unsigned enc[32];
  if(!skip){
    #pragma unroll
    for(int j=0;j<8;j++){
      float4 v = *(const float4*)&src[col0 + j*4];
      enc[j*4+0]=fenc(v.x); enc[j*4+1]=fenc(v.y); enc[j*4+2]=fenc(v.z); enc[j*4+3]=fenc(v.w);
    }
    #pragma unroll
    for(int j=0;j<32;j++) atomicAdd(&hist[enc[j] >> 20], 1u);
  } else {
    #pragma unroll
    for(int j=0;j<32;j++) enc[j] = 0u;
  }
  __syncthreads();
  unsigned lsum = 0u;
  #pragma unroll
  for(int j=0;j<16;j++) lsum += hist[t*16 + j];
  unsigned v = lsum;
  #pragma unroll
  for(int o=1;o<64;o<<=1){
    unsigned u = (unsigned)__shfl_down((int)v, o, 64);
    if(lane + o < 64) v += u;
  }
  if(lane == 0) wtot[wid] = v;
  __syncthreads();
  unsigned cross = 0u;
  #pragma unroll
  for(int w2=0;w2<4;w2++) if(w2 > wid) cross += wtot[w2];
  unsigned Tinc = v + cross;
  unsigned above = Tinc - lsum;
  unsigned run = above;
  #pragma unroll
  for(int b=15;b>=0;b--){
    unsigned prev = run;
    run += hist[t*16 + b];
    if(run >= EXTRA && prev < EXTRA){ bc_bin = (unsigned)(t*16 + b); bc_need = EXTRA - prev; }
  }
  __syncthreads();
  unsigned pivotBin = bc_bin, needIn = bc_need;
  int gr = rbase + r;
  #pragma unroll
  for(int j=0;j<32;j++){
    unsigned e = enc[j];
    unsigned bin = e >> 20;
    if(bin > pivotBin){
      unsigned s = atomicAdd(&bc_cnt, 1u);
      topv2[gr*EXTRA + s] = fdec(e);
      topi2[gr*EXTRA + s] = col0 + j;
    } else if(bin == pivotBin){
      unsigned ci = atomicAdd(&bc_c, 1u);
      if(ci < CAND_CAP){ candE[ci] = e; candC[ci] = (unsigned short)(col0 + j); }
    }
  }
  __syncthreads();
  unsigned c = bc_c;
  if(c <= CAND_CAP){
    for(unsigned i=t; i<c; i+=256){
      unsigned ei = candE[i]; unsigned coli = candC[i];
      unsigned rank = 0;
      for(unsigned j2=0;j2<c;j2++){
        unsigned ej = candE[j2];
        rank += (ej > ei) || (ej == ei && candC[j2] < coli);
      }
      if(rank < needIn){
        unsigned s = atomicAdd(&bc_cnt, 1u);
        topv2[gr*EXTRA + s] = fdec(ei);
        topi2[gr*EXTRA + s] = (int)coli;
      }
    }
  } else {
    // rare fallback: 8/8/4-bit radix over pivot-bin elements
    unsigned* h256  = hist;
    unsigned* scanb = hist + 1024;
    unsigned prefix = pivotBin;
    unsigned need = needIn;
    const int shifts[3] = {12, 4, 0};
    const unsigned masks[3] = {255u, 255u, 15u};
    const int nbins[3] = {256, 256, 16};
    for(int p=0;p<3;p++){
      int sh = shifts[p]; unsigned mk = masks[p]; int nb = nbins[p];
      if(t < nb) h256[t] = 0u;
      __syncthreads();
      #pragma unroll
      for(int j=0;j<32;j++){
        unsigned e = enc[j];
        int pshift = (p==0)? 20 : (p==1? 12 : 4);
        if((e >> pshift) == prefix) atomicAdd(&h256[(e>>sh)&mk], 1u);
      }
      __syncthreads();
      unsigned vv = (t < nb) ? h256[t] : 0u;
      for(int o=1;o<nb;o<<=1){
        if(t < nb) scanb[t] = vv;
        __syncthreads();
        if(t < nb && t+o < nb) vv += scanb[t+o];
        __syncthreads();
      }
      if(t < nb) scanb[t] = vv;
      __syncthreads();
      if(t < nb){
        unsigned nxt = (t < nb-1) ? scanb[t+1] : 0u;
        if(vv >= need && nxt < need){ bc_bin = (prefix << ((p==2)?4:8)) | (unsigned)t; bc_need = need - nxt; }
      }
      __syncthreads();
      prefix = bc_bin; need = bc_need;
      __syncthreads();
    }
    unsigned pivotEnc = prefix;
    unsigned needTies = need;
    unsigned tie_local = 0u;
    #pragma unroll
    for(int j=0;j<32;j++){
      unsigned e = enc[j];
      if((e >> 20) == pivotBin){
        if(e > pivotEnc){
          unsigned s = atomicAdd(&bc_cnt, 1u);
          topv2[gr*EXTRA + s] = fdec(e);
          topi2[gr*EXTRA + s] = col0 + j;
        } else if(e == pivotEnc) tie_local++;
      }
    }
    unsigned iv = tie_local;
    for(int o=1;o<256;o<<=1){
      scanb[t] = iv; __syncthreads();
      if(t >= o) iv += scanb[t-o];
      __syncthreads();
    }
    unsigned rank = iv - tie_local;
    #pragma unroll
    for(int j=0;j<32;j++){
      unsigned e = enc[j];
      if(e == pivotEnc && (e >> 20) == pivotBin){
        if(rank < needTies){
          unsigned s = atomicAdd(&bc_cnt, 1u);
          topv2[gr*EXTRA + s] = fdec(e);
          topi2[gr*EXTRA + s] = col0 + j;
        }
        rank++;
      }
    }
  }
}

// ---------------- h2 = g@W2, attention logits (rows < BN only) ----------------
// Rows >= BN of h2/a2i/a2j are never consumed: layer-2 sources are < BN and
// edges with dst >= BN are guarded out (agg2[dst>=BN] unused by the head).
__global__ void k_h2(const float* __restrict__ g, const float* __restrict__ W2,
                     const float* __restrict__ ai2w, const float* __restrict__ aj2w,
                     float* __restrict__ h2, float* __restrict__ a2i, float* __restrict__ a2j){
  int r = blockIdx.x, d = threadIdx.x;
  __shared__ float gr[Dd];
  gr[d] = g[(size_t)r*Dd + d];
  __syncthreads();
  float hv = 0.f;
  #pragma unroll
  for(int k=0;k<Dd;k++) hv += gr[k]*W2[k*Dd + d];
  h2[(size_t)r*Dd + d] = hv;
  float a = hv*ai2w[d];
  float b = hv*aj2w[d];
  for(int o=32;o>0;o>>=1){ a += __shfl_down(a,o,64); b += __shfl_down(b,o,64); }
  if(d==0){ a2i[r]=a; a2j[r]=b; }
}

// ---------------- layer-2 edge scores + segment max ----------------
// Only dst < BN matter: reference uses relu(agg2)[:BN] only.
__global__ void k_s2(const float* __restrict__ a2i, const float* __restrict__ a2j,
                     const float* __restrict__ topv2, const int* __restrict__ topi2,
                     float* __restrict__ s2, unsigned int* __restrict__ segmax){
  int e = blockIdx.x*256 + threadIdx.x;
  if(e >= BN*EXTRA) return;
  int r = e/EXTRA;
  int dst = topi2[e];
  if(dst >= BN) return;
  float sc = a2i[dst] + a2j[r];
  sc = sc >= 0.f ? sc : SLOPE*sc;
  sc *= topv2[e];
  s2[e] = sc;
  atomicMax(&segmax[dst], fenc(sc));
}

// ---------------- exp + segment sum ----------------
__global__ void k_e2(const float* __restrict__ s2, const int* __restrict__ topi2,
                     const unsigned int* __restrict__ segmax,
                     float* __restrict__ e2, float* __restrict__ ssum){
  int e = blockIdx.x*256 + threadIdx.x;
  if(e >= BN*EXTRA) return;
  int dst = topi2[e];
  if(dst >= BN) return;
  float m = fdec(segmax[dst]);
  float v = expf(s2[e] - m);
  e2[e] = v;
  atomicAdd(&ssum[dst], v);
}

// ---------------- weighted scatter into agg2 ----------------
__global__ void k_scat(const float* __restrict__ e2, const float* __restrict__ ssum,
                       const int* __restrict__ topi2, const float* __restrict__ h2,
                       float* __restrict__ agg2){
  int idx = blockIdx.x*256 + threadIdx.x;
  int e = idx >> 6, d = idx & 63;
  int dst = topi2[e];
  if(dst >= BN) return;
  int src = e/EXTRA;
  float alpha = e2[e]/fmaxf(ssum[dst], 1e-12f);
  atomicAdd(&agg2[(size_t)dst*Dd + d], alpha*h2[(size_t)src*Dd + d]);
}

// ---------------- head stats over x3 = relu(agg2+bias2)*emb ----------------
__global__ void k_headstats(const float* __restrict__ agg2, const float* __restrict__ bias2,
                            const float* __restrict__ emb, float* __restrict__ mu2, float* __restrict__ var2){
  int c = blockIdx.x, t = threadIdx.x;
  float bc = bias2[c];
  float s = 0.f, s2 = 0.f;
  for(int r=t; r<BN; r+=256){
    float v = fmaxf(agg2[(size_t)r*Dd + c] + bc, 0.f) * emb[(r & (Nn-1))*Dd + c];
    s += v; s2 += v*v;
  }
  __shared__ float ls[256], ls2[256];
  ls[t]=s; ls2[t]=s2; __syncthreads();
  for(int o=128;o>0;o>>=1){
    if(t<o){ ls[t]+=ls[t+o]; ls2[t]+=ls2[t+o]; }
    __syncthreads();
  }
  if(t==0){ float m=ls[0]/BN; mu2[c]=m; var2[c]=ls2[0]/BN - m*m; }
}

// ---------------- final: BN + relu + Linear(D,1) ----------------
__global__ void k_out(const float* __restrict__ agg2, const float* __restrict__ bias2,
                      const float* __restrict__ emb, const float* __restrict__ mu2,
                      const float* __restrict__ var2, const float* __restrict__ gO,
                      const float* __restrict__ bO, const float* __restrict__ Wout,
                      const float* __restrict__ bout, float* __restrict__ out){
  int r = blockIdx.x, d = threadIdx.x;
  float v = fmaxf(agg2[(size_t)r*Dd + d] + bias2[d], 0.f) * emb[(r & (Nn-1))*Dd + d];
  float y = gO[d]*(v - mu2[d])/sqrtf(var2[d]+EPS) + bO[d];
  y = fmaxf(y, 0.f)*Wout[d];
  for(int o=32;o>0;o>>=1) y += __shfl_down(y, o, 64);
  if(d==0) out[r] = y + bout[0];
}

extern "C" void kernel_launch(void* const* d_in, const int* in_sizes, int n_in,
                              void* d_out, int out_size, void* d_ws, size_t ws_size,
                              hipStream_t stream){
  const float* data  = (const float*)d_in[0];
  const float* emb   = (const float*)d_in[1];
  const float* W1    = (const float*)d_in[2];
  const float* ai1   = (const float*)d_in[3];
  const float* aj1   = (const float*)d_in[4];
  const float* bias1 = (const float*)d_in[5];
  const float* bn1g  = (const float*)d_in[6];
  const float* bn1b  = (const float*)d_in[7];
  const float* P     = (const float*)d_in[8];
  const float* W2    = (const float*)d_in[9];
  const float* ai2w  = (const float*)d_in[10];
  const float* aj2w  = (const float*)d_in[11];
  const float* bias2 = (const float*)d_in[12];
  const float* bnOg  = (const float*)d_in[13];
  const float* bnOb  = (const float*)d_in[14];
  const float* Wout  = (const float*)d_in[15];
  const float* bout  = (const float*)d_in[16];
  float* out = (float*)d_out;

  char* w = (char*)d_ws;
  auto alloc = [&](size_t nbytes)->char*{
    char* p = w; w += (nbytes + 255) & ~(size_t)255; return p;
  };
  float* norms1 = (float*)alloc(Nn*4);
  float* topv1  = (float*)alloc(Nn*TOPK*4);
  int*   topi1  = (int*)  alloc(Nn*TOPK*4);
  float* h      = (float*)alloc((size_t)BN*Dd*4);
  float* si     = (float*)alloc(BN*4);
  float* sj     = (float*)alloc(BN*4);
  float* agg1   = (float*)alloc((size_t)BN*Dd*4);
  float* mu1    = (float*)alloc(Dd*4);
  float* var1   = (float*)alloc(Dd*4);
  float* g      = (float*)alloc((size_t)TBN*Dd*4);
  float* gn     = (float*)alloc((size_t)TBN*Dd*4);
  float* topv2  = (float*)alloc((size_t)BN*EXTRA*4);
  int*   topi2  = (int*)  alloc((size_t)BN*EXTRA*4);
  float* h2     = (float*)alloc((size_t)TBN*Dd*4);
  float* a2i    = (float*)alloc(TBN*4);
  float* a2j    = (float*)alloc(TBN*4);
  float* s2     = (float*)alloc((size_t)BN*EXTRA*4);
  float* e2     = (float*)alloc((size_t)BN*EXTRA*4);
  // contiguous zero region: agg2 | ssum | segmax
  float* zblock = (float*)alloc(((size_t)TBN*Dd + TBN + TBN)*4);
  float* agg2   = zblock;
  float* ssum   = zblock + (size_t)TBN*Dd;
  unsigned int* segmax = (unsigned int*)(ssum + TBN);
  float* mu2    = (float*)alloc(Dd*4);
  float* var2   = (float*)alloc(Dd*4);
  float* efpart = (float*)alloc((size_t)RC*BN*Dd*4);   // 16 MB split-K partials
  float* SmaxB  = (float*)alloc((size_t)4096*512*4);   // per-row 16-col subtile maxima (8 MB)

  // adaptive S-chunk (multiple of 128 rows; prefer one big chunk)
  size_t used = (size_t)(w - (char*)d_ws);
  size_t rem  = ws_size > used ? ws_size - used : 0;
  int chunkRows = 4096;
  while(chunkRows > 128 && (size_t)chunkRows*TBN*4 > rem) chunkRows >>= 1;
  float* Schunk = (float*)alloc((size_t)chunkRows*TBN*4);

  // ---- layer 1 ----
  k_emb_norm<<<Nn, 64, 0, stream>>>(emb, norms1);
  k_emb_topk<<<Nn, Nn, 0, stream>>>(emb, norms1, topv1, topi1);
  k_h1<<<BN, 64, 0, stream>>>(data, emb, W1, ai1, aj1, h, si, sj);
  k_agg1<<<BN, 64, 0, stream>>>(h, si, sj, topv1, topi1, bias1, agg1);
  k_colstats<<<Dd, 256, 0, stream>>>(agg1, mu1, var1);
  k_bnrelu1<<<(BN*Dd)/256, 256, 0, stream>>>(agg1, mu1, var1, bn1g, bn1b, g);

  // ---- ef = P^T gcn : split-K, no atomics ----
  k_ef1<<<dim3(BN/128, RC), 256, 0, stream>>>(P, g, efpart);
  k_ef2<<<(BN*Dd/4)/256, 256, 0, stream>>>(efpart, g + (size_t)BN*Dd);

  // ---- cos2 top-25: normalized rows + fp32 GEMM (+16-col maxima) + tile-skip radix ----
  k_gn<<<TBN, 64, 0, stream>>>(g, gn);
  for(int rbase=0; rbase<BN; rbase+=chunkRows){
    k_sgemm<<<dim3(TBN/128, chunkRows/128), 256, 0, stream>>>(gn, rbase, Schunk, SmaxB);
    k_radix<<<chunkRows, 256, 0, stream>>>(Schunk, SmaxB, rbase, topv2, topi2);
  }

  // ---- layer 2 ----
  k_h2<<<BN, 64, 0, stream>>>(g, W2, ai2w, aj2w, h2, a2i, a2j);
  k_zero<<<((TBN*Dd + 2*TBN) + 255)/256, 256, 0, stream>>>(zblock, TBN*Dd + 2*TBN);
  k_s2<<<(BN*EXTRA + 255)/256, 256, 0, stream>>>(a2i, a2j, topv2, topi2, s2, segmax);
  k_e2<<<(BN*EXTRA + 255)/256, 256, 0, stream>>>(s2, topi2, segmax, e2, ssum);
  k_scat<<<(BN*EXTRA*Dd)/256, 256, 0, stream>>>(e2, ssum, topi2, h2, agg2);

  // ---- head ----
  k_headstats<<<Dd, 256, 0, stream>>>(agg2, bias2, emb, mu2, var2);
  k_out<<<BN, 64, 0, stream>>>(agg2, bias2, emb, mu2, var2, bnOg, bnOb, Wout, bout, out);
}

// Round 15
// 349.237 us; speedup vs baseline: 2.3935x; 1.0184x over previous
//
#include <hip/hip_runtime.h>
#include <hip/hip_bf16.h>
#include <math.h>

#define DEV __device__ __forceinline__

constexpr int Bb   = 32;
constexpr int Nn   = 128;
constexpr int Ff   = 10;
constexpr int Dd   = 64;
constexpr int TOPK = 20;
constexpr int EXTRA= 25;
constexpr int BN   = 4096;   // B*N
constexpr int TBN  = 8192;   // 2*BN
constexpr int RC   = 16;     // r-chunks for split-K ef
constexpr int CAND_CAP = 1024;
constexpr float EPS   = 1e-5f;
constexpr float SLOPE = 0.2f;

// order-preserving float<->uint encoding (monotone: a<b  <=> fenc(a)<fenc(b))
DEV unsigned int fenc(float f){
  unsigned int b = __float_as_uint(f);
  return (b & 0x80000000u) ? ~b : (b | 0x80000000u);
}
DEV float fdec(unsigned int u){
  unsigned int b = (u & 0x80000000u) ? (u & 0x7FFFFFFFu) : ~u;
  return __uint_as_float(b);
}

// ---------------- generic zero ----------------
__global__ void k_zero(float* __restrict__ p, int n){
  int i = blockIdx.x*256 + threadIdx.x;
  if(i < n) p[i] = 0.f;
}

// ---------------- emb row norms ----------------
__global__ void k_emb_norm(const float* __restrict__ emb, float* __restrict__ norms){
  int i = blockIdx.x, d = threadIdx.x;
  float v = emb[i*Dd + d];
  float s = v*v;
  for(int o=32;o>0;o>>=1) s += __shfl_down(s, o, 64);
  if(d==0) norms[i] = fmaxf(sqrtf(s), 1e-12f);
}

// ---------------- emb cosine + top-20 per row: single-pass rank select ----------------
__global__ void k_emb_topk(const float* __restrict__ emb, const float* __restrict__ norms,
                           float* __restrict__ topv, int* __restrict__ topi){
  __shared__ float se[Dd];
  __shared__ float sc[Nn];
  int i = blockIdx.x, t = threadIdx.x;
  if(t < Dd) se[t] = emb[i*Dd + t];
  __syncthreads();
  float dot = 0.f;
  for(int d=0; d<Dd; d++) dot += se[d]*emb[t*Dd + d];
  float v = dot/(norms[i]*norms[t]);
  sc[t] = v;
  __syncthreads();
  int rank = 0;
  for(int j=0; j<Nn; j++){
    float vj = sc[j];
    rank += (vj > v) || (vj == v && j < t);
  }
  if(rank < TOPK){
    topv[i*TOPK + rank] = v;
    topi[i*TOPK + rank] = t;
  }
}

// ---------------- h = x@W1, si/sj attention logits ----------------
__global__ void k_h1(const float* __restrict__ data, const float* __restrict__ emb,
                     const float* __restrict__ W1, const float* __restrict__ ai1,
                     const float* __restrict__ aj1,
                     float* __restrict__ h, float* __restrict__ si, float* __restrict__ sj){
  int r = blockIdx.x, d = threadIdx.x;
  int node = r & (Nn-1);
  __shared__ float xr[Ff];
  if(d < Ff) xr[d] = data[r*Ff + d];
  __syncthreads();
  float hv = 0.f;
  #pragma unroll
  for(int f=0; f<Ff; f++) hv += xr[f]*W1[f*Dd + d];
  h[r*Dd + d] = hv;
  float e = emb[node*Dd + d];
  float a = hv*ai1[d] + e*ai1[Dd + d];
  float b = hv*aj1[d] + e*aj1[Dd + d];
  for(int o=32;o>0;o>>=1){ a += __shfl_down(a,o,64); b += __shfl_down(b,o,64); }
  if(d==0){ si[r] = a; sj[r] = b; }
}

// ---------------- layer-1 segment softmax + aggregation ----------------
__global__ void k_agg1(const float* __restrict__ h, const float* __restrict__ si,
                       const float* __restrict__ sj, const float* __restrict__ topv,
                       const int* __restrict__ topi, const float* __restrict__ bias1,
                       float* __restrict__ agg){
  int r = blockIdx.x, d = threadIdx.x;
  int b = r >> 7, node = r & (Nn-1);
  __shared__ float sal[TOPK];
  __shared__ int   ssrc[TOPK];
  if(d < TOPK){
    int s = b*Nn + topi[node*TOPK + d];
    float sc = si[r] + sj[s];
    sc = sc >= 0.f ? sc : SLOPE*sc;
    sal[d] = sc * topv[node*TOPK + d];
    ssrc[d] = s;
  }
  __syncthreads();
  float m = -INFINITY;
  #pragma unroll
  for(int k=0;k<TOPK;k++) m = fmaxf(m, sal[k]);
  float al[TOPK]; float ssum = 0.f;
  #pragma unroll
  for(int k=0;k<TOPK;k++){ al[k] = expf(sal[k]-m); ssum += al[k]; }
  float inv = 1.0f/fmaxf(ssum, 1e-12f);
  float acc = 0.f;
  #pragma unroll
  for(int k=0;k<TOPK;k++) acc += al[k]*inv*h[ssrc[k]*Dd + d];
  agg[r*Dd + d] = acc + bias1[d];
}

// ---------------- per-channel stats over BN rows (agg1) ----------------
__global__ void k_colstats(const float* __restrict__ x, float* __restrict__ mu, float* __restrict__ var){
  int c = blockIdx.x, t = threadIdx.x;
  float s = 0.f, s2 = 0.f;
  for(int r=t; r<BN; r+=256){ float v = x[r*Dd + c]; s += v; s2 += v*v; }
  __shared__ float ls[256], ls2[256];
  ls[t]=s; ls2[t]=s2; __syncthreads();
  for(int o=128;o>0;o>>=1){
    if(t<o){ ls[t]+=ls[t+o]; ls2[t]+=ls2[t+o]; }
    __syncthreads();
  }
  if(t==0){ float m = ls[0]/BN; mu[c]=m; var[c]=ls2[0]/BN - m*m; }
}

// ---------------- BN1 + relu -> g[0:BN], fused row-normalize -> gn[0:BN] ----------------
// Per-row blocks (64 threads). Same shuffle-tree norm as the old k_gn:
// bit-identical g and gn.
__global__ void k_bnrelu1(const float* __restrict__ agg, const float* __restrict__ mu,
                          const float* __restrict__ var, const float* __restrict__ gamma,
                          const float* __restrict__ beta,
                          float* __restrict__ g, float* __restrict__ gn){
  int r = blockIdx.x, d = threadIdx.x;
  float v = agg[(size_t)r*Dd + d];
  float y = gamma[d]*(v - mu[d])/sqrtf(var[d]+EPS) + beta[d];
  y = fmaxf(y, 0.f);
  g[(size_t)r*Dd + d] = y;
  float s = y*y;
  for(int o=32;o>0;o>>=1) s += __shfl_down(s, o, 64);
  s = __shfl(s, 0, 64);
  float inv = 1.0f/fmaxf(sqrtf(s), 1e-12f);
  gn[(size_t)r*Dd + d] = y*inv;
}

// ---------------- ef stage 1: partial P^T @ gcn tiles, non-atomic ----------------
// 128-wide j-tile, acc[8][4]/thread: 1.5 B LDS read per FMA (was 2.0),
// 2x FMA per staged byte. Fragment reads bank-conflict-free
// (Pt broadcast at banks {0,8,16,24}; Gt 2-way = free).
__global__ __launch_bounds__(256) void k_ef1(const float* __restrict__ P, const float* __restrict__ gcn,
                                             float* __restrict__ part){
  __shared__ float Pt[16*128];
  __shared__ float Gt[16*64];
  int t = threadIdx.x;
  int jbase = blockIdx.x*128;
  int r0 = blockIdx.y*256;
  int row = t >> 4, col4 = (t & 15)*4;
  int tr = t >> 4, tc = t & 15;
  float acc[8][4] = {};
  for(int step=0; step<16; step++){
    int r = r0 + step*16;
    float4 pv0 = *(const float4*)&P[(size_t)(r+row)*BN + jbase + col4];
    float4 pv1 = *(const float4*)&P[(size_t)(r+row)*BN + jbase + col4 + 64];
    float4 gv  = *(const float4*)&gcn[(r+row)*Dd + col4];
    __syncthreads();
    *(float4*)&Pt[row*128 + col4]      = pv0;
    *(float4*)&Pt[row*128 + col4 + 64] = pv1;
    *(float4*)&Gt[row*64 + col4] = gv;
    __syncthreads();
    #pragma unroll
    for(int rr=0; rr<16; rr++){
      float4 pa0 = *(float4*)&Pt[rr*128 + tr*8];
      float4 pa1 = *(float4*)&Pt[rr*128 + tr*8 + 4];
      float4 gb  = *(float4*)&Gt[rr*64 + tc*4];
      float pav[8] = {pa0.x,pa0.y,pa0.z,pa0.w,pa1.x,pa1.y,pa1.z,pa1.w};
      float gbv[4] = {gb.x,gb.y,gb.z,gb.w};
      #pragma unroll
      for(int a=0;a<8;a++)
        #pragma unroll
        for(int b=0;b<4;b++) acc[a][b] += pav[a]*gbv[b];
    }
  }
  float* dst = part + ((size_t)blockIdx.y*BN + jbase)*Dd;
  #pragma unroll
  for(int a=0;a<8;a++){
    float4 v = make_float4(acc[a][0],acc[a][1],acc[a][2],acc[a][3]);
    *(float4*)&dst[(tr*8+a)*Dd + tc*4] = v;
  }
}

// ---------------- ef stage 2: reduce RC partials, fused row-normalize -> gn[BN:] ----
// Per-row blocks (64 threads). Ascending-c sum = identical order to the old
// float4 reduction; shuffle-tree norm identical to old k_gn -> bit-identical
// gn. g[BN:] was only ever read by the old k_gn, so its store is dropped.
__global__ void k_ef2(const float* __restrict__ part, float* __restrict__ gn){
  int r = blockIdx.x, d = threadIdx.x;
  float s = 0.f;
  #pragma unroll
  for(int c=0;c<RC;c++) s += part[(size_t)c*BN*Dd + (size_t)r*Dd + d];
  float q = s*s;
  for(int o=32;o>0;o>>=1) q += __shfl_down(q, o, 64);
  q = __shfl(q, 0, 64);
  float inv = 1.0f/fmaxf(sqrtf(q), 1e-12f);
  gn[(size_t)(BN + r)*Dd + d] = s*inv;
}

// ---------------- S chunk GEMM (fp32+LDS, K-split staging) + 16-col Smax ----------------
// 128x128 tile/block, 256 threads, per-thread 2x2 blocks of 4x4 (all LDS
// fragment reads ds_read_b128). K=64 staged in TWO K=32 stages so LDS is
// 32 KB -> ~5 blocks/CU (was 2 at 64 KB; occupancy 17.8% was the binding
// counter). Staging writes use m0=t&31 -> 2-way bank alias (free; was 4-way).
// Accumulation order (ascending k) unchanged -> bit-identical S/Smax.
__global__ __launch_bounds__(256) void k_sgemm(const float* __restrict__ gn,
                                               int rbase, float* __restrict__ S,
                                               float* __restrict__ Smax){
  __shared__ __align__(16) float A[32*128];    // [k][row], one K-stage
  __shared__ __align__(16) float Bs[32*128];   // [k][col]
  int t = threadIdx.x;
  int ctile = blockIdx.x*128;
  int rtile = rbase + blockIdx.y*128;
  int q2 = t >> 5, m0 = t & 31;   // q2: k-quad 0..7, m0: row base 0..31
  int tr = t >> 4;                // 0..15 -> row block
  int tc = t & 15;                // 0..15 -> col block
  float acc[8][8] = {};
  #pragma unroll
  for(int s=0; s<2; s++){
    if(s) __syncthreads();
    #pragma unroll
    for(int l=0;l<4;l++){
      int m = m0 + 32*l;
      float4 av = *(const float4*)&gn[(size_t)(rtile+m)*Dd + s*32 + q2*4];
      float4 bv = *(const float4*)&gn[(size_t)(ctile+m)*Dd + s*32 + q2*4];
      A[(q2*4+0)*128 + m] = av.x; A[(q2*4+1)*128 + m] = av.y;
      A[(q2*4+2)*128 + m] = av.z; A[(q2*4+3)*128 + m] = av.w;
      Bs[(q2*4+0)*128 + m] = bv.x; Bs[(q2*4+1)*128 + m] = bv.y;
      Bs[(q2*4+2)*128 + m] = bv.z; Bs[(q2*4+3)*128 + m] = bv.w;
    }
    __syncthreads();
    #pragma unroll 4
    for(int k=0;k<32;k++){
      float4 a0 = *(const float4*)&A[k*128 + tr*4];
      float4 a1 = *(const float4*)&A[k*128 + tr*4 + 64];
      float4 b0 = *(const float4*)&Bs[k*128 + tc*4];
      float4 b1 = *(const float4*)&Bs[k*128 + tc*4 + 64];
      float a[8] = {a0.x,a0.y,a0.z,a0.w,a1.x,a1.y,a1.z,a1.w};
      float b[8] = {b0.x,b0.y,b0.z,b0.w,b1.x,b1.y,b1.z,b1.w};
      #pragma unroll
      for(int i=0;i<8;i++)
        #pragma unroll
        for(int j=0;j<8;j++) acc[i][j] += a[i]*b[j];
    }
  }
  int rloc = blockIdx.y*128;
  // Per row, 16-col subtile maxima (8 per 128-col block) for k_radix's
  // fine-grain exact tile-skip; then float4 S stores.
  #pragma unroll
  for(int i=0;i<8;i++){
    int rl = tr*4 + (i&3) + (i>>2)*64;
    int r  = rloc + rl;
    float mL = fmaxf(fmaxf(acc[i][0],acc[i][1]), fmaxf(acc[i][2],acc[i][3]));
    float mR = fmaxf(fmaxf(acc[i][4],acc[i][5]), fmaxf(acc[i][6],acc[i][7]));
    #pragma unroll
    for(int o=1;o<4;o<<=1){
      mL = fmaxf(mL, __shfl_xor(mL, o, 64));
      mR = fmaxf(mR, __shfl_xor(mR, o, 64));
    }
    if((tc & 3) == 0){
      Smax[(size_t)r*512 + blockIdx.x*8 + (tc>>2)]     = mL;
      Smax[(size_t)r*512 + blockIdx.x*8 + 4 + (tc>>2)] = mR;
    }
    float4 v0 = make_float4(acc[i][0],acc[i][1],acc[i][2],acc[i][3]);
    float4 v1 = make_float4(acc[i][4],acc[i][5],acc[i][6],acc[i][7]);
    *(float4*)&S[(size_t)r*TBN + ctile + tc*4]      = v0;
    *(float4*)&S[(size_t)r*TBN + ctile + tc*4 + 64] = v1;
  }
}

// ---------------- exact top-25 per row with 16-col tile-skip ----------------
// L = 25th-largest of the row's 64 (128-col) tile maxima is a lower bound on
// the 25th value (those top-25 maxima ARE 25 row values >= L). Skip any
// 16-col subtile whose max < L: its values are < L <= V25 and cannot enter
// the top-25 or perturb pivot counts. Skipped slots encode as 0u (bin 0);
// real cosines have fenc bin >= 1031 -> exact.
__global__ __launch_bounds__(256) void k_radix(const float* __restrict__ S,
                                               const float* __restrict__ Smax,
                                               int rbase,
                                               float* __restrict__ topv2, int* __restrict__ topi2){
  __shared__ unsigned hist[4096];
  __shared__ unsigned wtot[4];
  __shared__ unsigned candE[CAND_CAP];
  __shared__ unsigned short candC[CAND_CAP];
  __shared__ unsigned bc_bin, bc_need, bc_cnt, bc_c;
  __shared__ float st16[512];
  __shared__ float stmax[64];
  __shared__ float sLsh;
  int t = threadIdx.x;
  int lane = t & 63, wid = t >> 6;
  int r = blockIdx.x;
  const float* src = S + (size_t)r*TBN;
  int col0 = t*32;

  st16[t]       = Smax[(size_t)r*512 + t];
  st16[256 + t] = Smax[(size_t)r*512 + 256 + t];
  #pragma unroll
  for(int j=0;j<16;j++) hist[t*16 + j] = 0u;
  if(t==0){ bc_cnt = 0u; bc_c = 0u; }
  __syncthreads();
  if(t < 64){
    float m = st16[t*8];
    #pragma unroll
    for(int k=1;k<8;k++) m = fmaxf(m, st16[t*8 + k]);
    stmax[t] = m;
  }
  __syncthreads();
  if(t < 64){
    float mi = stmax[t];
    int cnt = 0;
    for(int j=0;j<64;j++){
      float mj = stmax[j];
      cnt += (mj > mi) || (mj == mi && j < t);
    }
    if(cnt == 24) sLsh = mi;
  }
  __syncthreads();
  float L = sLsh;
  // thread t covers cols [t*32, t*32+32) = subtiles 2t, 2t+1
  bool skip = fmaxf(st16[t*2], st16[t*2+1]) < L;

  unsigned enc[32];
  if(!skip){
    #pragma unroll
    for(int j=0;j<8;j++){
      float4 v = *(const float4*)&src[col0 + j*4];
      enc[j*4+0]=fenc(v.x); enc[j*4+1]=fenc(v.y); enc[j*4+2]=fenc(v.z); enc[j*4+3]=fenc(v.w);
    }
    #pragma unroll
    for(int j=0;j<32;j++) atomicAdd(&hist[enc[j] >> 20], 1u);
  } else {
    #pragma unroll
    for(int j=0;j<32;j++) enc[j] = 0u;
  }
  __syncthreads();
  unsigned lsum = 0u;
  #pragma unroll
  for(int j=0;j<16;j++) lsum += hist[t*16 + j];
  unsigned v = lsum;
  #pragma unroll
  for(int o=1;o<64;o<<=1){
    unsigned u = (unsigned)__shfl_down((int)v, o, 64);
    if(lane + o < 64) v += u;
  }
  if(lane == 0) wtot[wid] = v;
  __syncthreads();
  unsigned cross = 0u;
  #pragma unroll
  for(int w2=0;w2<4;w2++) if(w2 > wid) cross += wtot[w2];
  unsigned Tinc = v + cross;
  unsigned above = Tinc - lsum;
  unsigned run = above;
  #pragma unroll
  for(int b=15;b>=0;b--){
    unsigned prev = run;
    run += hist[t*16 + b];
    if(run >= EXTRA && prev < EXTRA){ bc_bin = (unsigned)(t*16 + b); bc_need = EXTRA - prev; }
  }
  __syncthreads();
  unsigned pivotBin = bc_bin, needIn = bc_need;
  int gr = rbase + r;
  #pragma unroll
  for(int j=0;j<32;j++){
    unsigned e = enc[j];
    unsigned bin = e >> 20;
    if(bin > pivotBin){
      unsigned s = atomicAdd(&bc_cnt, 1u);
      topv2[gr*EXTRA + s] = fdec(e);
      topi2[gr*EXTRA + s] = col0 + j;
    } else if(bin == pivotBin){
      unsigned ci = atomicAdd(&bc_c, 1u);
      if(ci < CAND_CAP){ candE[ci] = e; candC[ci] = (unsigned short)(col0 + j); }
    }
  }
  __syncthreads();
  unsigned c = bc_c;
  if(c <= CAND_CAP){
    for(unsigned i=t; i<c; i+=256){
      unsigned ei = candE[i]; unsigned coli = candC[i];
      unsigned rank = 0;
      for(unsigned j2=0;j2<c;j2++){
        unsigned ej = candE[j2];
        rank += (ej > ei) || (ej == ei && candC[j2] < coli);
      }
      if(rank < needIn){
        unsigned s = atomicAdd(&bc_cnt, 1u);
        topv2[gr*EXTRA + s] = fdec(ei);
        topi2[gr*EXTRA + s] = (int)coli;
      }
    }
  } else {
    // rare fallback: 8/8/4-bit radix over pivot-bin elements
    unsigned* h256  = hist;
    unsigned* scanb = hist + 1024;
    unsigned prefix = pivotBin;
    unsigned need = needIn;
    const int shifts[3] = {12, 4, 0};
    const unsigned masks[3] = {255u, 255u, 15u};
    const int nbins[3] = {256, 256, 16};
    for(int p=0;p<3;p++){
      int sh = shifts[p]; unsigned mk = masks[p]; int nb = nbins[p];
      if(t < nb) h256[t] = 0u;
      __syncthreads();
      #pragma unroll
      for(int j=0;j<32;j++){
        unsigned e = enc[j];
        int pshift = (p==0)? 20 : (p==1? 12 : 4);
        if((e >> pshift) == prefix) atomicAdd(&h256[(e>>sh)&mk], 1u);
      }
      __syncthreads();
      unsigned vv = (t < nb) ? h256[t] : 0u;
      for(int o=1;o<nb;o<<=1){
        if(t < nb) scanb[t] = vv;
        __syncthreads();
        if(t < nb && t+o < nb) vv += scanb[t+o];
        __syncthreads();
      }
      if(t < nb) scanb[t] = vv;
      __syncthreads();
      if(t < nb){
        unsigned nxt = (t < nb-1) ? scanb[t+1] : 0u;
        if(vv >= need && nxt < need){ bc_bin = (prefix << ((p==2)?4:8)) | (unsigned)t; bc_need = need - nxt; }
      }
      __syncthreads();
      prefix = bc_bin; need = bc_need;
      __syncthreads();
    }
    unsigned pivotEnc = prefix;
    unsigned needTies = need;
    unsigned tie_local = 0u;
    #pragma unroll
    for(int j=0;j<32;j++){
      unsigned e = enc[j];
      if((e >> 20) == pivotBin){
        if(e > pivotEnc){
          unsigned s = atomicAdd(&bc_cnt, 1u);
          topv2[gr*EXTRA + s] = fdec(e);
          topi2[gr*EXTRA + s] = col0 + j;
        } else if(e == pivotEnc) tie_local++;
      }
    }
    unsigned iv = tie_local;
    for(int o=1;o<256;o<<=1){
      scanb[t] = iv; __syncthreads();
      if(t >= o) iv += scanb[t-o];
      __syncthreads();
    }
    unsigned rank = iv - tie_local;
    #pragma unroll
    for(int j=0;j<32;j++){
      unsigned e = enc[j];
      if(e == pivotEnc && (e >> 20) == pivotBin){
        if(rank < needTies){
          unsigned s = atomicAdd(&bc_cnt, 1u);
          topv2[gr*EXTRA + s] = fdec(e);
          topi2[gr*EXTRA + s] = col0 + j;
        }
        rank++;
      }
    }
  }
}

// ---------------- h2 = g@W2, attention logits (rows < BN only) ----------------
// Rows >= BN of h2/a2i/a2j are never consumed: layer-2 sources are < BN and
// edges with dst >= BN are guarded out (agg2[dst>=BN] unused by the head).
__global__ void k_h2(const float* __restrict__ g, const float* __restrict__ W2,
                     const float* __restrict__ ai2w, const float* __restrict__ aj2w,
                     float* __restrict__ h2, float* __restrict__ a2i, float* __restrict__ a2j){
  int r = blockIdx.x, d = threadIdx.x;
  __shared__ float gr[Dd];
  gr[d] = g[(size_t)r*Dd + d];
  __syncthreads();
  float hv = 0.f;
  #pragma unroll
  for(int k=0;k<Dd;k++) hv += gr[k]*W2[k*Dd + d];
  h2[(size_t)r*Dd + d] = hv;
  float a = hv*ai2w[d];
  float b = hv*aj2w[d];
  for(int o=32;o>0;o>>=1){ a += __shfl_down(a,o,64); b += __shfl_down(b,o,64); }
  if(d==0){ a2i[r]=a; a2j[r]=b; }
}

// ---------------- layer-2 edge scores + segment max ----------------
// Only dst < BN matter: reference uses relu(agg2)[:BN] only.
__global__ void k_s2(const float* __restrict__ a2i, const float* __restrict__ a2j,
                     const float* __restrict__ topv2, const int* __restrict__ topi2,
                     float* __restrict__ s2, unsigned int* __restrict__ segmax){
  int e = blockIdx.x*256 + threadIdx.x;
  if(e >= BN*EXTRA) return;
  int r = e/EXTRA;
  int dst = topi2[e];
  if(dst >= BN) return;
  float sc = a2i[dst] + a2j[r];
  sc = sc >= 0.f ? sc : SLOPE*sc;
  sc *= topv2[e];
  s2[e] = sc;
  atomicMax(&segmax[dst], fenc(sc));
}

// ---------------- exp + segment sum ----------------
__global__ void k_e2(const float* __restrict__ s2, const int* __restrict__ topi2,
                     const unsigned int* __restrict__ segmax,
                     float* __restrict__ e2, float* __restrict__ ssum){
  int e = blockIdx.x*256 + threadIdx.x;
  if(e >= BN*EXTRA) return;
  int dst = topi2[e];
  if(dst >= BN) return;
  float m = fdec(segmax[dst]);
  float v = expf(s2[e] - m);
  e2[e] = v;
  atomicAdd(&ssum[dst], v);
}

// ---------------- weighted scatter into agg2 ----------------
__global__ void k_scat(const float* __restrict__ e2, const float* __restrict__ ssum,
                       const int* __restrict__ topi2, const float* __restrict__ h2,
                       float* __restrict__ agg2){
  int idx = blockIdx.x*256 + threadIdx.x;
  int e = idx >> 6, d = idx & 63;
  int dst = topi2[e];
  if(dst >= BN) return;
  int src = e/EXTRA;
  float alpha = e2[e]/fmaxf(ssum[dst], 1e-12f);
  atomicAdd(&agg2[(size_t)dst*Dd + d], alpha*h2[(size_t)src*Dd + d]);
}

// ---------------- head stats over x3 = relu(agg2+bias2)*emb ----------------
__global__ void k_headstats(const float* __restrict__ agg2, const float* __restrict__ bias2,
                            const float* __restrict__ emb, float* __restrict__ mu2, float* __restrict__ var2){
  int c = blockIdx.x, t = threadIdx.x;
  float bc = bias2[c];
  float s = 0.f, s2 = 0.f;
  for(int r=t; r<BN; r+=256){
    float v = fmaxf(agg2[(size_t)r*Dd + c] + bc, 0.f) * emb[(r & (Nn-1))*Dd + c];
    s += v; s2 += v*v;
  }
  __shared__ float ls[256], ls2[256];
  ls[t]=s; ls2[t]=s2; __syncthreads();
  for(int o=128;o>0;o>>=1){
    if(t<o){ ls[t]+=ls[t+o]; ls2[t]+=ls2[t+o]; }
    __syncthreads();
  }
  if(t==0){ float m=ls[0]/BN; mu2[c]=m; var2[c]=ls2[0]/BN - m*m; }
}

// ---------------- final: BN + relu + Linear(D,1) ----------------
__global__ void k_out(const float* __restrict__ agg2, const float* __restrict__ bias2,
                      const float* __restrict__ emb, const float* __restrict__ mu2,
                      const float* __restrict__ var2, const float* __restrict__ gO,
                      const float* __restrict__ bO, const float* __restrict__ Wout,
                      const float* __restrict__ bout, float* __restrict__ out){
  int r = blockIdx.x, d = threadIdx.x;
  float v = fmaxf(agg2[(size_t)r*Dd + d] + bias2[d], 0.f) * emb[(r & (Nn-1))*Dd + d];
  float y = gO[d]*(v - mu2[d])/sqrtf(var2[d]+EPS) + bO[d];
  y = fmaxf(y, 0.f)*Wout[d];
  for(int o=32;o>0;o>>=1) y += __shfl_down(y, o, 64);
  if(d==0) out[r] = y + bout[0];
}

extern "C" void kernel_launch(void* const* d_in, const int* in_sizes, int n_in,
                              void* d_out, int out_size, void* d_ws, size_t ws_size,
                              hipStream_t stream){
  const float* data  = (const float*)d_in[0];
  const float* emb   = (const float*)d_in[1];
  const float* W1    = (const float*)d_in[2];
  const float* ai1   = (const float*)d_in[3];
  const float* aj1   = (const float*)d_in[4];
  const float* bias1 = (const float*)d_in[5];
  const float* bn1g  = (const float*)d_in[6];
  const float* bn1b  = (const float*)d_in[7];
  const float* P     = (const float*)d_in[8];
  const float* W2    = (const float*)d_in[9];
  const float* ai2w  = (const float*)d_in[10];
  const float* aj2w  = (const float*)d_in[11];
  const float* bias2 = (const float*)d_in[12];
  const float* bnOg  = (const float*)d_in[13];
  const float* bnOb  = (const float*)d_in[14];
  const float* Wout  = (const float*)d_in[15];
  const float* bout  = (const float*)d_in[16];
  float* out = (float*)d_out;

  char* w = (char*)d_ws;
  auto alloc = [&](size_t nbytes)->char*{
    char* p = w; w += (nbytes + 255) & ~(size_t)255; return p;
  };
  float* norms1 = (float*)alloc(Nn*4);
  float* topv1  = (float*)alloc(Nn*TOPK*4);
  int*   topi1  = (int*)  alloc(Nn*TOPK*4);
  float* h      = (float*)alloc((size_t)BN*Dd*4);
  float* si     = (float*)alloc(BN*4);
  float* sj     = (float*)alloc(BN*4);
  float* agg1   = (float*)alloc((size_t)BN*Dd*4);
  float* mu1    = (float*)alloc(Dd*4);
  float* var1   = (float*)alloc(Dd*4);
  float* g      = (float*)alloc((size_t)TBN*Dd*4);
  float* gn     = (float*)alloc((size_t)TBN*Dd*4);
  float* topv2  = (float*)alloc((size_t)BN*EXTRA*4);
  int*   topi2  = (int*)  alloc((size_t)BN*EXTRA*4);
  float* h2     = (float*)alloc((size_t)TBN*Dd*4);
  float* a2i    = (float*)alloc(TBN*4);
  float* a2j    = (float*)alloc(TBN*4);
  float* s2     = (float*)alloc((size_t)BN*EXTRA*4);
  float* e2     = (float*)alloc((size_t)BN*EXTRA*4);
  // contiguous zero region: agg2 | ssum | segmax
  float* zblock = (float*)alloc(((size_t)TBN*Dd + TBN + TBN)*4);
  float* agg2   = zblock;
  float* ssum   = zblock + (size_t)TBN*Dd;
  unsigned int* segmax = (unsigned int*)(ssum + TBN);
  float* mu2    = (float*)alloc(Dd*4);
  float* var2   = (float*)alloc(Dd*4);
  float* efpart = (float*)alloc((size_t)RC*BN*Dd*4);   // 16 MB split-K partials
  float* SmaxB  = (float*)alloc((size_t)4096*512*4);   // per-row 16-col subtile maxima (8 MB)

  // adaptive S-chunk (multiple of 128 rows; prefer one big chunk)
  size_t used = (size_t)(w - (char*)d_ws);
  size_t rem  = ws_size > used ? ws_size - used : 0;
  int chunkRows = 4096;
  while(chunkRows > 128 && (size_t)chunkRows*TBN*4 > rem) chunkRows >>= 1;
  float* Schunk = (float*)alloc((size_t)chunkRows*TBN*4);

  // ---- layer 1 ----
  k_emb_norm<<<Nn, 64, 0, stream>>>(emb, norms1);
  k_emb_topk<<<Nn, Nn, 0, stream>>>(emb, norms1, topv1, topi1);
  k_h1<<<BN, 64, 0, stream>>>(data, emb, W1, ai1, aj1, h, si, sj);
  k_agg1<<<BN, 64, 0, stream>>>(h, si, sj, topv1, topi1, bias1, agg1);
  k_colstats<<<Dd, 256, 0, stream>>>(agg1, mu1, var1);
  k_bnrelu1<<<BN, 64, 0, stream>>>(agg1, mu1, var1, bn1g, bn1b, g, gn);

  // ---- ef = P^T gcn : split-K, no atomics; ef2 fuses gn[BN:] normalize ----
  k_ef1<<<dim3(BN/128, RC), 256, 0, stream>>>(P, g, efpart);
  k_ef2<<<BN, 64, 0, stream>>>(efpart, gn);

  // ---- cos2 top-25: fp32 GEMM (K-split staging, +16-col maxima) + tile-skip radix ----
  for(int rbase=0; rbase<BN; rbase+=chunkRows){
    k_sgemm<<<dim3(TBN/128, chunkRows/128), 256, 0, stream>>>(gn, rbase, Schunk, SmaxB);
    k_radix<<<chunkRows, 256, 0, stream>>>(Schunk, SmaxB, rbase, topv2, topi2);
  }

  // ---- layer 2 ----
  k_h2<<<BN, 64, 0, stream>>>(g, W2, ai2w, aj2w, h2, a2i, a2j);
  k_zero<<<((TBN*Dd + 2*TBN) + 255)/256, 256, 0, stream>>>(zblock, TBN*Dd + 2*TBN);
  k_s2<<<(BN*EXTRA + 255)/256, 256, 0, stream>>>(a2i, a2j, topv2, topi2, s2, segmax);
  k_e2<<<(BN*EXTRA + 255)/256, 256, 0, stream>>>(s2, topi2, segmax, e2, ssum);
  k_scat<<<(BN*EXTRA*Dd)/256, 256, 0, stream>>>(e2, ssum, topi2, h2, agg2);

  // ---- head ----
  k_headstats<<<Dd, 256, 0, stream>>>(agg2, bias2, emb, mu2, var2);
  k_out<<<BN, 64, 0, stream>>>(agg2, bias2, emb, mu2, var2, bnOg, bnOb, Wout, bout, out);
}